// Round 3
// baseline (752.963 us; speedup 1.0000x reference)
//
#include <hip/hip_runtime.h>

#define DEG 16
#define F_IN 128
#define H 32

__device__ __forceinline__ float relu_f(float x) { return fmaxf(x, 0.0f); }

// bf16 round-to-nearest-even pack/unpack (values are finite; post-relu for vals1)
__device__ __forceinline__ unsigned short f2bf(float x) {
    unsigned u = __float_as_uint(x);
    u += 0x7FFFu + ((u >> 16) & 1u);
    return (unsigned short)(u >> 16);
}
__device__ __forceinline__ float bf2f(unsigned short h) {
    return __uint_as_float(((unsigned)h) << 16);
}

// ---------------------------------------------------------------------------
// Kernel A0 (unchanged, proven): Xn1[i] = relu((Asum[i]/D[i]) @ wn1p^T + bn1p + bn1s)
// X0 == zeros so the self term is bias only. One block (128 thr) per node.
// ---------------------------------------------------------------------------
__global__ __launch_bounds__(F_IN) void k_xn1(
    const float* __restrict__ X, const int* __restrict__ dst,
    const float* __restrict__ D,
    const float* __restrict__ wn1p, const float* __restrict__ bn1p,
    const float* __restrict__ bn1s,
    float* __restrict__ Xn1)
{
    const int i = blockIdx.x;
    const int t = threadIdx.x;
    __shared__ int ds[DEG];
    __shared__ float As[F_IN];
    if (t < DEG) ds[t] = dst[i * DEG + t];
    __syncthreads();
    const float xi = X[(size_t)i * F_IN + t];
    float s = 0.0f;
#pragma unroll
    for (int j = 0; j < DEG; ++j)
        s += fabsf(xi - X[(size_t)ds[j] * F_IN + t]);
    s *= (1.0f / D[i]);
    As[t] = s;
    __syncthreads();
    const int o = t >> 2, q = t & 3;
    float p = 0.0f;
#pragma unroll
    for (int kk = 0; kk < 32; ++kk)
        p += As[q * 32 + kk] * wn1p[o * F_IN + q * 32 + kk];
    p += __shfl_xor(p, 1);
    p += __shfl_xor(p, 2);
    if (q == 0) Xn1[(size_t)i * H + o] = relu_f(p + bn1p[o] + bn1s[o]);
}

// ---------------------------------------------------------------------------
// Kernel B (fused t1 + edge_conv1 + node_conv2):
//   t1A/B = |X[src]-X[dst]| @ we1s^T          (never materialized in HBM)
//   vals1 = relu(t1 + b1 + x1@Wa^T + x2@Wb^T) -> stored bf16
//   Xn2   = relu((sum_16 vals1 / D) @ wn2p^T + Xn1 @ wn2s^T + b2)
// 2 edges (same node) per thread, 8 threads per node.
// NO early returns: node clamped, all shuffles run with full lane groups,
// global stores predicated on act.
// ---------------------------------------------------------------------------
__global__ __launch_bounds__(256) void k_fuse1(
    const float* __restrict__ X, const int* __restrict__ dst,
    const float* __restrict__ D,
    const float* __restrict__ we1s,
    const float* __restrict__ we1p, const float* __restrict__ be1p,
    const float* __restrict__ be1s,
    const float* __restrict__ wn2p, const float* __restrict__ bn2p,
    const float* __restrict__ wn2s, const float* __restrict__ bn2s,
    const float* __restrict__ Xn1,
    unsigned short* __restrict__ vals1, float* __restrict__ Xn2, int N)
{
    __shared__ float Ws[H * F_IN];                        // we1s, 16 KiB
    __shared__ float Wa[H * H], Wb[H * H];                // folded we1p
    __shared__ float W2p[H * H], W2s[H * H];
    __shared__ float b1[H], b2[H];
    const int tid = threadIdx.x;
#pragma unroll
    for (int r = 0; r < (H * F_IN) / 256; ++r)
        Ws[r * 256 + tid] = we1s[r * 256 + tid];
#pragma unroll
    for (int r = 0; r < (H * H) / 256; ++r) {
        const int idx = r * 256 + tid;
        const int o = idx >> 5, k = idx & 31;
        const float w1 = we1p[o * 2 * H + k];
        const float w2 = we1p[o * 2 * H + H + k];
        Wa[idx] = 0.5f * (w1 + w2);
        Wb[idx] = 0.5f * (w2 - w1);
        W2p[idx] = wn2p[idx];
        W2s[idx] = wn2s[idx];
    }
    if (tid < H) { b1[tid] = be1p[tid] + be1s[tid]; b2[tid] = bn2p[tid] + bn2s[tid]; }
    __syncthreads();

    const int node0 = blockIdx.x * 32 + (tid >> 3);
    const bool act = (node0 < N);
    const int node = act ? node0 : (N - 1);      // clamp: loads stay in bounds
    const int q = tid & 7;
    const long e0 = (long)node * DEG + q * 2;    // src[e] == e/16 by construction
    const int dA = dst[e0];
    const int dB = dst[e0 + 1];

    // ---- phase A: t1 for the 2 edges (F_IN-dot per output, weights LDS) ----
    const float4* __restrict__ Xi4 = (const float4*)(X + (size_t)node * F_IN);
    const float4* __restrict__ XA4 = (const float4*)(X + (size_t)dA * F_IN);
    const float4* __restrict__ XB4 = (const float4*)(X + (size_t)dB * F_IN);
    const float4* __restrict__ Ws4 = (const float4*)Ws;
    float tA[H], tB[H];
#pragma unroll
    for (int o = 0; o < H; ++o) { tA[o] = 0.0f; tB[o] = 0.0f; }
    for (int c = 0; c < F_IN / 4; ++c) {
        const float4 xi = Xi4[c];
        const float4 ya = XA4[c];
        const float4 yb = XB4[c];
        const float aA0 = fabsf(xi.x - ya.x), aA1 = fabsf(xi.y - ya.y);
        const float aA2 = fabsf(xi.z - ya.z), aA3 = fabsf(xi.w - ya.w);
        const float aB0 = fabsf(xi.x - yb.x), aB1 = fabsf(xi.y - yb.y);
        const float aB2 = fabsf(xi.z - yb.z), aB3 = fabsf(xi.w - yb.w);
#pragma unroll
        for (int o = 0; o < H; ++o) {
            const float4 w = Ws4[o * (F_IN / 4) + c];   // wave-uniform broadcast
            tA[o] += aA0 * w.x + aA1 * w.y + aA2 * w.z + aA3 * w.w;
            tB[o] += aB0 * w.x + aB1 * w.y + aB2 * w.z + aB3 * w.w;
        }
    }

    // ---- phase B: edge_conv1 -> vals1 (bf16), node sum -> Xn2 ----
    float x1[H], xA[H], xB[H];
    {
        const float4* p1 = (const float4*)(Xn1 + (size_t)node * H);
        const float4* pA = (const float4*)(Xn1 + (size_t)dA * H);
        const float4* pB = (const float4*)(Xn1 + (size_t)dB * H);
#pragma unroll
        for (int c = 0; c < H / 4; ++c) {
            float4 v = p1[c]; x1[4*c]=v.x; x1[4*c+1]=v.y; x1[4*c+2]=v.z; x1[4*c+3]=v.w;
            float4 u = pA[c]; xA[4*c]=u.x; xA[4*c+1]=u.y; xA[4*c+2]=u.z; xA[4*c+3]=u.w;
            float4 w = pB[c]; xB[4*c]=w.x; xB[4*c+1]=w.y; xB[4*c+2]=w.z; xB[4*c+3]=w.w;
        }
    }
    const float4* Wa4 = (const float4*)Wa;
    const float4* Wb4 = (const float4*)Wb;
#pragma unroll
    for (int o = 0; o < H; ++o) {
        float sS = 0.0f, sA = 0.0f, sB = 0.0f;
#pragma unroll
        for (int k4 = 0; k4 < H / 4; ++k4) {
            const float4 wa = Wa4[o * (H / 4) + k4];
            const float4 wb = Wb4[o * (H / 4) + k4];
            sS += x1[4*k4]*wa.x + x1[4*k4+1]*wa.y + x1[4*k4+2]*wa.z + x1[4*k4+3]*wa.w;
            sA += xA[4*k4]*wb.x + xA[4*k4+1]*wb.y + xA[4*k4+2]*wb.z + xA[4*k4+3]*wb.w;
            sB += xB[4*k4]*wb.x + xB[4*k4+1]*wb.y + xB[4*k4+2]*wb.z + xB[4*k4+3]*wb.w;
        }
        tA[o] = relu_f(tA[o] + b1[o] + sS + sA);   // vals1 for edge e0
        tB[o] = relu_f(tB[o] + b1[o] + sS + sB);   // vals1 for edge e0+1
    }
    if (act) {   // store vals1 bf16: 2 edges x 32 -> 8 x uint4
        uint4* pv = (uint4*)(vals1 + (size_t)e0 * H);
        uint4 u;
#pragma unroll
        for (int blk = 0; blk < 4; ++blk) {
            u.x = (unsigned)f2bf(tA[8*blk+0]) | ((unsigned)f2bf(tA[8*blk+1]) << 16);
            u.y = (unsigned)f2bf(tA[8*blk+2]) | ((unsigned)f2bf(tA[8*blk+3]) << 16);
            u.z = (unsigned)f2bf(tA[8*blk+4]) | ((unsigned)f2bf(tA[8*blk+5]) << 16);
            u.w = (unsigned)f2bf(tA[8*blk+6]) | ((unsigned)f2bf(tA[8*blk+7]) << 16);
            pv[blk] = u;
        }
#pragma unroll
        for (int blk = 0; blk < 4; ++blk) {
            u.x = (unsigned)f2bf(tB[8*blk+0]) | ((unsigned)f2bf(tB[8*blk+1]) << 16);
            u.y = (unsigned)f2bf(tB[8*blk+2]) | ((unsigned)f2bf(tB[8*blk+3]) << 16);
            u.z = (unsigned)f2bf(tB[8*blk+4]) | ((unsigned)f2bf(tB[8*blk+5]) << 16);
            u.w = (unsigned)f2bf(tB[8*blk+6]) | ((unsigned)f2bf(tB[8*blk+7]) << 16);
            pv[4 + blk] = u;
        }
    }
    // node sum of vals1 over 16 edges: 2-edge partial + 8-lane butterfly.
    // All 64 lanes execute (no early returns) -> full groups always.
#pragma unroll
    for (int o = 0; o < H; ++o) tA[o] += tB[o];
#pragma unroll
    for (int m = 1; m < 8; m <<= 1) {
#pragma unroll
        for (int o = 0; o < H; ++o) tA[o] += __shfl_xor(tA[o], m);
    }
    const float invD = 1.0f / D[node];
#pragma unroll
    for (int o = 0; o < H; ++o) tA[o] *= invD;
    if (act) {
        const float4* W2p4 = (const float4*)W2p;
        const float4* W2s4 = (const float4*)W2s;
#pragma unroll
        for (int rep = 0; rep < 4; ++rep) {
            const int o = q * 4 + rep;
            float a2 = b2[o];
#pragma unroll
            for (int k4 = 0; k4 < H / 4; ++k4) {
                const float4 wp = W2p4[o * (H / 4) + k4];
                const float4 ws = W2s4[o * (H / 4) + k4];
                a2 += tA[4*k4]*wp.x + tA[4*k4+1]*wp.y + tA[4*k4+2]*wp.z + tA[4*k4+3]*wp.w;
                a2 += x1[4*k4]*ws.x + x1[4*k4+1]*ws.y + x1[4*k4+2]*ws.z + x1[4*k4+3]*ws.w;
            }
            Xn2[(size_t)node * H + o] = relu_f(a2);
        }
    }
}

// ---------------------------------------------------------------------------
// Kernel C: vals2 = relu(Ef2 @ we2p^T + be2p + vals1 @ we2s^T + be2s)
//           out[e] = sigmoid(vals2 @ wc^T + bc)
// 2 edges per thread; shared-src term computed once; vals1 read as bf16.
// No early returns; stores predicated.
// ---------------------------------------------------------------------------
__global__ __launch_bounds__(256) void k_edge2_out(
    const float* __restrict__ Xn2, const int* __restrict__ dst,
    const float* __restrict__ we2p, const float* __restrict__ be2p,
    const float* __restrict__ we2s, const float* __restrict__ be2s,
    const float* __restrict__ wc, const float* __restrict__ bc,
    const unsigned short* __restrict__ vals1, float* __restrict__ out, int N)
{
    __shared__ float Wa[H * H], Wb[H * H], Ws[H * H];
    __shared__ float b[H], wcl[H];
    const int tid = threadIdx.x;
#pragma unroll
    for (int r = 0; r < (H * H) / 256; ++r) {
        const int idx = r * 256 + tid;
        const int o = idx >> 5, k = idx & 31;
        const float w1 = we2p[o * 2 * H + k];
        const float w2 = we2p[o * 2 * H + H + k];
        Wa[idx] = 0.5f * (w1 + w2);
        Wb[idx] = 0.5f * (w2 - w1);
        Ws[idx] = we2s[idx];
    }
    if (tid < H) { b[tid] = be2p[tid] + be2s[tid]; wcl[tid] = wc[tid]; }
    __syncthreads();

    const int node0 = blockIdx.x * 32 + (tid >> 3);
    const bool act = (node0 < N);
    const int node = act ? node0 : (N - 1);
    const int q = tid & 7;
    const long e0 = (long)node * DEG + q * 2;
    const int dA = dst[e0];
    const int dB = dst[e0 + 1];

    float x1[H], xA[H], xB[H], vA[H], vB[H];
    {
        const float4* p1 = (const float4*)(Xn2 + (size_t)node * H);
        const float4* pA = (const float4*)(Xn2 + (size_t)dA * H);
        const float4* pB = (const float4*)(Xn2 + (size_t)dB * H);
#pragma unroll
        for (int c = 0; c < H / 4; ++c) {
            float4 v = p1[c]; x1[4*c]=v.x; x1[4*c+1]=v.y; x1[4*c+2]=v.z; x1[4*c+3]=v.w;
            float4 u = pA[c]; xA[4*c]=u.x; xA[4*c+1]=u.y; xA[4*c+2]=u.z; xA[4*c+3]=u.w;
            float4 w = pB[c]; xB[4*c]=w.x; xB[4*c+1]=w.y; xB[4*c+2]=w.z; xB[4*c+3]=w.w;
        }
        const uint4* pv = (const uint4*)(vals1 + (size_t)e0 * H);
#pragma unroll
        for (int blk = 0; blk < 4; ++blk) {
            const uint4 u = pv[blk];
            vA[8*blk+0] = bf2f((unsigned short)(u.x & 0xFFFF));
            vA[8*blk+1] = bf2f((unsigned short)(u.x >> 16));
            vA[8*blk+2] = bf2f((unsigned short)(u.y & 0xFFFF));
            vA[8*blk+3] = bf2f((unsigned short)(u.y >> 16));
            vA[8*blk+4] = bf2f((unsigned short)(u.z & 0xFFFF));
            vA[8*blk+5] = bf2f((unsigned short)(u.z >> 16));
            vA[8*blk+6] = bf2f((unsigned short)(u.w & 0xFFFF));
            vA[8*blk+7] = bf2f((unsigned short)(u.w >> 16));
        }
#pragma unroll
        for (int blk = 0; blk < 4; ++blk) {
            const uint4 u = pv[4 + blk];
            vB[8*blk+0] = bf2f((unsigned short)(u.x & 0xFFFF));
            vB[8*blk+1] = bf2f((unsigned short)(u.x >> 16));
            vB[8*blk+2] = bf2f((unsigned short)(u.y & 0xFFFF));
            vB[8*blk+3] = bf2f((unsigned short)(u.y >> 16));
            vB[8*blk+4] = bf2f((unsigned short)(u.z & 0xFFFF));
            vB[8*blk+5] = bf2f((unsigned short)(u.z >> 16));
            vB[8*blk+6] = bf2f((unsigned short)(u.w & 0xFFFF));
            vB[8*blk+7] = bf2f((unsigned short)(u.w >> 16));
        }
    }
    const float4* Wa4 = (const float4*)Wa;
    const float4* Wb4 = (const float4*)Wb;
    const float4* Ws4 = (const float4*)Ws;
    float sx0 = 0.0f, sx1 = 0.0f;
#pragma unroll
    for (int o = 0; o < H; ++o) {
        float sS = 0.0f, s0 = 0.0f, s1 = 0.0f;
#pragma unroll
        for (int k4 = 0; k4 < H / 4; ++k4) {
            const float4 wa = Wa4[o * (H / 4) + k4];
            const float4 wb = Wb4[o * (H / 4) + k4];
            const float4 ws = Ws4[o * (H / 4) + k4];
            sS += x1[4*k4]*wa.x + x1[4*k4+1]*wa.y + x1[4*k4+2]*wa.z + x1[4*k4+3]*wa.w;
            s0 += xA[4*k4]*wb.x + xA[4*k4+1]*wb.y + xA[4*k4+2]*wb.z + xA[4*k4+3]*wb.w;
            s0 += vA[4*k4]*ws.x + vA[4*k4+1]*ws.y + vA[4*k4+2]*ws.z + vA[4*k4+3]*ws.w;
            s1 += xB[4*k4]*wb.x + xB[4*k4+1]*wb.y + xB[4*k4+2]*wb.z + xB[4*k4+3]*wb.w;
            s1 += vB[4*k4]*ws.x + vB[4*k4+1]*ws.y + vB[4*k4+2]*ws.z + vB[4*k4+3]*ws.w;
        }
        sx0 += relu_f(b[o] + sS + s0) * wcl[o];
        sx1 += relu_f(b[o] + sS + s1) * wcl[o];
    }
    if (act) {
        const float bias = bc[0];
        float2 r;
        r.x = 1.0f / (1.0f + __expf(-(sx0 + bias)));
        r.y = 1.0f / (1.0f + __expf(-(sx1 + bias)));
        *(float2*)(out + e0) = r;
    }
}

// ---------------------------------------------------------------------------
extern "C" void kernel_launch(void* const* d_in, const int* in_sizes, int n_in,
                              void* d_out, int out_size, void* d_ws, size_t ws_size,
                              hipStream_t stream)
{
    const float* X    = (const float*)d_in[0];
    const int*   dst  = (const int*)  d_in[2];
    const float* D    = (const float*)d_in[3];
    const float* wn1p = (const float*)d_in[4];
    const float* bn1p = (const float*)d_in[5];
    // d_in[6] = wn1s unused: X0 == zeros, self term reduces to bn1s.
    const float* bn1s = (const float*)d_in[7];
    const float* we1p = (const float*)d_in[8];
    const float* be1p = (const float*)d_in[9];
    const float* we1s = (const float*)d_in[10];
    const float* be1s = (const float*)d_in[11];
    const float* wn2p = (const float*)d_in[12];
    const float* bn2p = (const float*)d_in[13];
    const float* wn2s = (const float*)d_in[14];
    const float* bn2s = (const float*)d_in[15];
    const float* we2p = (const float*)d_in[16];
    const float* be2p = (const float*)d_in[17];
    const float* we2s = (const float*)d_in[18];
    const float* be2s = (const float*)d_in[19];
    const float* wc   = (const float*)d_in[20];
    const float* bc   = (const float*)d_in[21];

    const int N = in_sizes[3];   // D has one entry per node

    // workspace (64.0 MB total, down from 115.2):
    //   [vals1 : N*DEG*H bf16 = 51.2MB][Xn1 : N*H fp32][Xn2 : N*H fp32]
    unsigned short* vals1 = (unsigned short*)d_ws;
    float* Xn1 = (float*)((char*)d_ws + (size_t)N * DEG * H * sizeof(unsigned short));
    float* Xn2 = Xn1 + (size_t)N * H;
    float* outp = (float*)d_out;

    const int nb32 = (N + 31) / 32;

    k_xn1<<<N, F_IN, 0, stream>>>(X, dst, D, wn1p, bn1p, bn1s, Xn1);
    k_fuse1<<<nb32, 256, 0, stream>>>(X, dst, D, we1s, we1p, be1p, be1s,
                                      wn2p, bn2p, wn2s, bn2s, Xn1, vals1, Xn2, N);
    k_edge2_out<<<nb32, 256, 0, stream>>>(Xn2, dst, we2p, be2p, we2s, be2s,
                                          wc, bc, vals1, outp, N);
}

// Round 4
// 414.764 us; speedup vs baseline: 1.8154x; 1.8154x over previous
//
#include <hip/hip_runtime.h>

#define DEG 16
#define F_IN 128
#define H 32

typedef __attribute__((ext_vector_type(8))) short bf16x8;   // 8 bf16 = 4 VGPRs (MFMA A/B frag)
typedef __attribute__((ext_vector_type(4))) float f32x4;    // MFMA C/D frag
typedef __attribute__((ext_vector_type(4))) int i32x4;

union Pk8 { i32x4 i; bf16x8 h; };

__device__ __forceinline__ float relu_f(float x) { return fmaxf(x, 0.0f); }

// bf16 round-to-nearest-even pack/unpack
__device__ __forceinline__ unsigned short f2bf(float x) {
    unsigned u = __float_as_uint(x);
    u += 0x7FFFu + ((u >> 16) & 1u);
    return (unsigned short)(u >> 16);
}
__device__ __forceinline__ float bf2f(unsigned short h) {
    return __uint_as_float(((unsigned)h) << 16);
}
__device__ __forceinline__ unsigned pk2(float a, float b) {
    return (unsigned)f2bf(a) | ((unsigned)f2bf(b) << 16);
}
// load 8 bf16 (16B aligned) -> 8 floats
__device__ __forceinline__ void ld8bf(const unsigned short* p, float* o) {
    const i32x4 u = *(const i32x4*)p;
#pragma unroll
    for (int i = 0; i < 4; ++i) {
        o[2 * i]     = bf2f((unsigned short)(u[i] & 0xFFFF));
        o[2 * i + 1] = bf2f((unsigned short)((unsigned)u[i] >> 16));
    }
}

// ---------------------------------------------------------------------------
// Prep: fold concat 0.5-factors into bf16 weight blocks, pre-sum biases.
//  Wcat1[32][192]: k<128 -> we1s[n][k]; 128..159 -> 0.5*we1p[n][k-128] (diff);
//                  160..191 -> 0.5*we1p[n][32+k-160] (sum)
//  Wcat2[32][96]:  k<32 -> 0.5*we2p[n][k]; 32..63 -> 0.5*we2p[n][32+k-32];
//                  64..95 -> we2s[n][k-64]
// ---------------------------------------------------------------------------
__global__ __launch_bounds__(256) void k_prep(
    const float* __restrict__ we1s, const float* __restrict__ we1p,
    const float* __restrict__ be1p, const float* __restrict__ be1s,
    const float* __restrict__ we2p, const float* __restrict__ we2s,
    const float* __restrict__ be2p, const float* __restrict__ be2s,
    unsigned short* __restrict__ Wcat1, unsigned short* __restrict__ Wcat2,
    float* __restrict__ bias1, float* __restrict__ bias2)
{
    const int tid = threadIdx.x;
    for (int idx = tid; idx < 32 * 192; idx += 256) {
        const int n = idx / 192, k = idx - n * 192;
        float w;
        if (k < 128)       w = we1s[n * 128 + k];
        else if (k < 160)  w = 0.5f * we1p[n * 64 + (k - 128)];
        else               w = 0.5f * we1p[n * 64 + 32 + (k - 160)];
        Wcat1[idx] = f2bf(w);
    }
    for (int idx = tid; idx < 32 * 96; idx += 256) {
        const int n = idx / 96, k = idx - n * 96;
        float w;
        if (k < 32)       w = 0.5f * we2p[n * 64 + k];
        else if (k < 64)  w = 0.5f * we2p[n * 64 + 32 + (k - 32)];
        else              w = we2s[n * 32 + (k - 64)];
        Wcat2[idx] = f2bf(w);
    }
    if (tid < H) {
        bias1[tid] = be1p[tid] + be1s[tid];
        bias2[tid] = be2p[tid] + be2s[tid];
    }
}

// ---------------------------------------------------------------------------
// Kernel A0 (proven structure): Xn1 = relu((Asum0/D)@wn1p^T + bn1p + bn1s),
// stored bf16. One block (128 thr) per node.
// ---------------------------------------------------------------------------
__global__ __launch_bounds__(F_IN) void k_xn1(
    const float* __restrict__ X, const int* __restrict__ dst,
    const float* __restrict__ D,
    const float* __restrict__ wn1p, const float* __restrict__ bn1p,
    const float* __restrict__ bn1s,
    unsigned short* __restrict__ Xn1b)
{
    const int i = blockIdx.x;
    const int t = threadIdx.x;
    __shared__ int ds[DEG];
    __shared__ float As[F_IN];
    if (t < DEG) ds[t] = dst[i * DEG + t];
    __syncthreads();
    const float xi = X[(size_t)i * F_IN + t];
    float s = 0.0f;
#pragma unroll
    for (int j = 0; j < DEG; ++j)
        s += fabsf(xi - X[(size_t)ds[j] * F_IN + t]);
    s *= (1.0f / D[i]);
    As[t] = s;
    __syncthreads();
    const int o = t >> 2, q = t & 3;
    float p = 0.0f;
#pragma unroll
    for (int kk = 0; kk < 32; ++kk)
        p += As[q * 32 + kk] * wn1p[o * F_IN + q * 32 + kk];
    p += __shfl_xor(p, 1);
    p += __shfl_xor(p, 2);
    if (q == 0) Xn1b[(size_t)i * H + o] = f2bf(relu_f(p + bn1p[o] + bn1s[o]));
}

// ---------------------------------------------------------------------------
// Kernel B (MFMA): one wave = one node = 16 edges.
//   In[e][0:128]   = |X[src]-X[dst]|
//   In[e][128:160] = Xn1[src]-Xn1[dst]   (0.5 folded into Wcat1)
//   In[e][160:192] = Xn1[src]+Xn1[dst]
//   vals1[e][:]    = relu(In @ Wcat1 + bias1)        -> bf16
//   Asum[node][:]  = sum over the 16 edges (fp32, pre-quantization)
// A-frag built in registers from 16B/32B gathers; B-frags loaded once.
// ---------------------------------------------------------------------------
__global__ __launch_bounds__(256) void k_layer1(
    const float* __restrict__ X, const int* __restrict__ dst,
    const unsigned short* __restrict__ Xn1b,
    const unsigned short* __restrict__ Wcat1, const float* __restrict__ bias1,
    unsigned short* __restrict__ vals1, float* __restrict__ Asum, int N)
{
    const int wave = threadIdx.x >> 6;
    const int lane = threadIdx.x & 63;
    const int node = blockIdx.x * 4 + wave;
    if (node >= N) return;                 // wave-uniform
    const int m = lane & 15, g = lane >> 4;
    const int e = node * DEG + m;
    const int d = dst[e];

    bf16x8 Bf[6][2];
#pragma unroll
    for (int kb = 0; kb < 6; ++kb)
#pragma unroll
        for (int t = 0; t < 2; ++t)
            Bf[kb][t] = *(const bf16x8*)(Wcat1 + (t * 16 + m) * 192 + kb * 32 + g * 8);

    f32x4 c0 = {0.f, 0.f, 0.f, 0.f}, c1 = {0.f, 0.f, 0.f, 0.f};
    const float* Xs = X + (size_t)node * F_IN;
    const float* Xd = X + (size_t)d * F_IN;
#pragma unroll
    for (int kb = 0; kb < 4; ++kb) {
        const int koff = kb * 32 + g * 8;
        const float4 s0 = *(const float4*)(Xs + koff);
        const float4 s1 = *(const float4*)(Xs + koff + 4);
        const float4 t0 = *(const float4*)(Xd + koff);
        const float4 t1 = *(const float4*)(Xd + koff + 4);
        Pk8 a;
        a.i[0] = pk2(fabsf(s0.x - t0.x), fabsf(s0.y - t0.y));
        a.i[1] = pk2(fabsf(s0.z - t0.z), fabsf(s0.w - t0.w));
        a.i[2] = pk2(fabsf(s1.x - t1.x), fabsf(s1.y - t1.y));
        a.i[3] = pk2(fabsf(s1.z - t1.z), fabsf(s1.w - t1.w));
        c0 = __builtin_amdgcn_mfma_f32_16x16x32_bf16(a.h, Bf[kb][0], c0, 0, 0, 0);
        c1 = __builtin_amdgcn_mfma_f32_16x16x32_bf16(a.h, Bf[kb][1], c1, 0, 0, 0);
    }
    {   // Ef1 part: diff (kb=4) and sum (kb=5) of Xn1 rows
        float x1v[8], x2v[8];
        ld8bf(Xn1b + (size_t)node * H + g * 8, x1v);
        ld8bf(Xn1b + (size_t)d * H + g * 8, x2v);
        Pk8 ad, aS;
#pragma unroll
        for (int i = 0; i < 4; ++i) {
            ad.i[i] = pk2(x1v[2 * i] - x2v[2 * i], x1v[2 * i + 1] - x2v[2 * i + 1]);
            aS.i[i] = pk2(x1v[2 * i] + x2v[2 * i], x1v[2 * i + 1] + x2v[2 * i + 1]);
        }
        c0 = __builtin_amdgcn_mfma_f32_16x16x32_bf16(ad.h, Bf[4][0], c0, 0, 0, 0);
        c1 = __builtin_amdgcn_mfma_f32_16x16x32_bf16(ad.h, Bf[4][1], c1, 0, 0, 0);
        c0 = __builtin_amdgcn_mfma_f32_16x16x32_bf16(aS.h, Bf[5][0], c0, 0, 0, 0);
        c1 = __builtin_amdgcn_mfma_f32_16x16x32_bf16(aS.h, Bf[5][1], c1, 0, 0, 0);
    }
    // epilogue: C layout col=lane&15 (=n), row=(lane>>4)*4+reg (=edge offset)
    const float b0 = bias1[m], b1v = bias1[16 + m];
    float sum0 = 0.f, sum1 = 0.f;
#pragma unroll
    for (int r = 0; r < 4; ++r) {
        const size_t erow = (size_t)(node * DEG + g * 4 + r) * H;
        const float v0 = relu_f(c0[r] + b0);
        const float v1 = relu_f(c1[r] + b1v);
        vals1[erow + m] = f2bf(v0);
        vals1[erow + 16 + m] = f2bf(v1);
        sum0 += v0; sum1 += v1;
    }
    sum0 += __shfl_xor(sum0, 16); sum0 += __shfl_xor(sum0, 32);
    sum1 += __shfl_xor(sum1, 16); sum1 += __shfl_xor(sum1, 32);
    if (g == 0) {
        Asum[(size_t)node * H + m] = sum0;
        Asum[(size_t)node * H + 16 + m] = sum1;
    }
}

// ---------------------------------------------------------------------------
// Kernel B2: Xn2 = relu((Asum/D)@wn2p^T + Xn1@wn2s^T + bn2p + bn2s) -> bf16
// 256 threads = 8 nodes x 32 outputs; weights + inputs staged in LDS.
// ---------------------------------------------------------------------------
__global__ __launch_bounds__(256) void k_xn2(
    const unsigned short* __restrict__ Xn1b, const float* __restrict__ Asum,
    const float* __restrict__ D,
    const float* __restrict__ wn2p, const float* __restrict__ bn2p,
    const float* __restrict__ wn2s, const float* __restrict__ bn2s,
    unsigned short* __restrict__ Xn2b, int N)
{
    __shared__ float Wp[H * H], Wsl[H * H], b2s[H];
    __shared__ float As[8 * H], Xl[8 * H];
    const int tid = threadIdx.x;
#pragma unroll
    for (int r = 0; r < 4; ++r) {
        const int idx = r * 256 + tid;
        Wp[idx] = wn2p[idx];
        Wsl[idx] = wn2s[idx];
    }
    if (tid < H) b2s[tid] = bn2p[tid] + bn2s[tid];
    {
        const int nl = tid >> 5, k = tid & 31;
        int node = blockIdx.x * 8 + nl;
        if (node >= N) node = N - 1;
        As[tid] = Asum[(size_t)node * H + k] * (1.0f / D[node]);
        Xl[tid] = bf2f(Xn1b[(size_t)node * H + k]);
    }
    __syncthreads();
    const int nl = tid >> 5, o = tid & 31;
    const int node = blockIdx.x * 8 + nl;
    if (node < N) {
        float a = b2s[o];
        const float4* wp4 = (const float4*)(Wp + o * H);
        const float4* ws4 = (const float4*)(Wsl + o * H);
        const float4* av = (const float4*)(As + nl * H);
        const float4* xv = (const float4*)(Xl + nl * H);
#pragma unroll
        for (int k4 = 0; k4 < 8; ++k4) {
            const float4 w = wp4[k4], v = av[k4];
            a += v.x * w.x + v.y * w.y + v.z * w.z + v.w * w.w;
            const float4 w2 = ws4[k4], x = xv[k4];
            a += x.x * w2.x + x.y * w2.y + x.z * w2.z + x.w * w2.w;
        }
        Xn2b[(size_t)node * H + o] = f2bf(relu_f(a));
    }
}

// ---------------------------------------------------------------------------
// Kernel C (MFMA): one wave = one node = 16 edges.
//   In[e][0:32]  = Xn2[src]-Xn2[dst]  (0.5 folded)
//   In[e][32:64] = Xn2[src]+Xn2[dst]
//   In[e][64:96] = vals1[e]           (bf16 direct -> A frag, no convert)
//   vals2 = relu(In @ Wcat2 + bias2);  out[e] = sigmoid(vals2 @ wc + bc)
// Classifier: row-reduce C-tile across 16 col-lanes (shfl_xor 1,2,4,8).
// ---------------------------------------------------------------------------
__global__ __launch_bounds__(256) void k_layer2(
    const unsigned short* __restrict__ Xn2b, const int* __restrict__ dst,
    const unsigned short* __restrict__ vals1,
    const unsigned short* __restrict__ Wcat2, const float* __restrict__ bias2,
    const float* __restrict__ wc, const float* __restrict__ bc,
    float* __restrict__ out, int N)
{
    const int wave = threadIdx.x >> 6;
    const int lane = threadIdx.x & 63;
    const int node = blockIdx.x * 4 + wave;
    if (node >= N) return;                 // wave-uniform
    const int m = lane & 15, g = lane >> 4;
    const int e = node * DEG + m;
    const int d = dst[e];

    bf16x8 Bf[3][2];
#pragma unroll
    for (int kb = 0; kb < 3; ++kb)
#pragma unroll
        for (int t = 0; t < 2; ++t)
            Bf[kb][t] = *(const bf16x8*)(Wcat2 + (t * 16 + m) * 96 + kb * 32 + g * 8);

    f32x4 c0 = {0.f, 0.f, 0.f, 0.f}, c1 = {0.f, 0.f, 0.f, 0.f};
    {
        float x1v[8], x2v[8];
        ld8bf(Xn2b + (size_t)node * H + g * 8, x1v);
        ld8bf(Xn2b + (size_t)d * H + g * 8, x2v);
        Pk8 ad, aS;
#pragma unroll
        for (int i = 0; i < 4; ++i) {
            ad.i[i] = pk2(x1v[2 * i] - x2v[2 * i], x1v[2 * i + 1] - x2v[2 * i + 1]);
            aS.i[i] = pk2(x1v[2 * i] + x2v[2 * i], x1v[2 * i + 1] + x2v[2 * i + 1]);
        }
        c0 = __builtin_amdgcn_mfma_f32_16x16x32_bf16(ad.h, Bf[0][0], c0, 0, 0, 0);
        c1 = __builtin_amdgcn_mfma_f32_16x16x32_bf16(ad.h, Bf[0][1], c1, 0, 0, 0);
        c0 = __builtin_amdgcn_mfma_f32_16x16x32_bf16(aS.h, Bf[1][0], c0, 0, 0, 0);
        c1 = __builtin_amdgcn_mfma_f32_16x16x32_bf16(aS.h, Bf[1][1], c1, 0, 0, 0);
    }
    {   // vals1 slice: already bf16 in A-frag order
        const bf16x8 av = *(const bf16x8*)(vals1 + (size_t)e * H + g * 8);
        c0 = __builtin_amdgcn_mfma_f32_16x16x32_bf16(av, Bf[2][0], c0, 0, 0, 0);
        c1 = __builtin_amdgcn_mfma_f32_16x16x32_bf16(av, Bf[2][1], c1, 0, 0, 0);
    }
    const float b0 = bias2[m], b1v = bias2[16 + m];
    const float w0 = wc[m], w1 = wc[16 + m];
    float sr[4];
#pragma unroll
    for (int r = 0; r < 4; ++r)
        sr[r] = relu_f(c0[r] + b0) * w0 + relu_f(c1[r] + b1v) * w1;
#pragma unroll
    for (int mask = 1; mask < 16; mask <<= 1) {
#pragma unroll
        for (int r = 0; r < 4; ++r)
            sr[r] += __shfl_xor(sr[r], mask);
    }
    if (m == 0) {
        const float bb = bc[0];
        float4 o4;
        o4.x = 1.0f / (1.0f + __expf(-(sr[0] + bb)));
        o4.y = 1.0f / (1.0f + __expf(-(sr[1] + bb)));
        o4.z = 1.0f / (1.0f + __expf(-(sr[2] + bb)));
        o4.w = 1.0f / (1.0f + __expf(-(sr[3] + bb)));
        *(float4*)(out + node * DEG + g * 4) = o4;
    }
}

// ---------------------------------------------------------------------------
extern "C" void kernel_launch(void* const* d_in, const int* in_sizes, int n_in,
                              void* d_out, int out_size, void* d_ws, size_t ws_size,
                              hipStream_t stream)
{
    const float* X    = (const float*)d_in[0];
    const int*   dst  = (const int*)  d_in[2];
    const float* D    = (const float*)d_in[3];
    const float* wn1p = (const float*)d_in[4];
    const float* bn1p = (const float*)d_in[5];
    // d_in[6] = wn1s unused: X0 == zeros, self term reduces to bn1s.
    const float* bn1s = (const float*)d_in[7];
    const float* we1p = (const float*)d_in[8];
    const float* be1p = (const float*)d_in[9];
    const float* we1s = (const float*)d_in[10];
    const float* be1s = (const float*)d_in[11];
    const float* wn2p = (const float*)d_in[12];
    const float* bn2p = (const float*)d_in[13];
    const float* wn2s = (const float*)d_in[14];
    const float* bn2s = (const float*)d_in[15];
    const float* we2p = (const float*)d_in[16];
    const float* be2p = (const float*)d_in[17];
    const float* we2s = (const float*)d_in[18];
    const float* be2s = (const float*)d_in[19];
    const float* wc   = (const float*)d_in[20];
    const float* bc   = (const float*)d_in[21];

    const int N = in_sizes[3];   // D has one entry per node
    const size_t E = (size_t)N * DEG;

    // ws layout (all 16B aligned):
    char* w = (char*)d_ws;
    unsigned short* vals1 = (unsigned short*)w;              w += E * H * 2;          // 51.2 MB
    unsigned short* Xn1b  = (unsigned short*)w;              w += (size_t)N * H * 2;  //  3.2 MB
    unsigned short* Xn2b  = (unsigned short*)w;              w += (size_t)N * H * 2;  //  3.2 MB
    float*          AsumP = (float*)w;                       w += (size_t)N * H * 4;  //  6.4 MB
    unsigned short* Wcat1 = (unsigned short*)w;              w += 32 * 192 * 2;
    unsigned short* Wcat2 = (unsigned short*)w;              w += 32 * 96 * 2;
    float*          bias1 = (float*)w;                       w += H * 4;
    float*          bias2 = (float*)w;                       w += H * 4;
    float* outp = (float*)d_out;

    const int nb4 = (N + 3) / 4;
    const int nb8 = (N + 7) / 8;

    k_prep<<<1, 256, 0, stream>>>(we1s, we1p, be1p, be1s, we2p, we2s, be2p, be2s,
                                  Wcat1, Wcat2, bias1, bias2);
    k_xn1<<<N, F_IN, 0, stream>>>(X, dst, D, wn1p, bn1p, bn1s, Xn1b);
    k_layer1<<<nb4, 256, 0, stream>>>(X, dst, Xn1b, Wcat1, bias1, vals1, AsumP, N);
    k_xn2<<<nb8, 256, 0, stream>>>(Xn1b, AsumP, D, wn2p, bn2p, wn2s, bn2s, Xn2b, N);
    k_layer2<<<nb4, 256, 0, stream>>>(Xn2b, dst, vals1, Wcat2, bias2, wc, bc, outp, N);
}

// Round 5
// 357.903 us; speedup vs baseline: 2.1038x; 1.1589x over previous
//
#include <hip/hip_runtime.h>
#include <hip/hip_bf16.h>

#define DEG 16
#define F_IN 128
#define H 32

typedef __attribute__((ext_vector_type(8))) short bf16x8;   // 8 bf16 = 4 VGPRs (MFMA A/B frag)
typedef __attribute__((ext_vector_type(4))) float f32x4;    // MFMA C/D frag
typedef __attribute__((ext_vector_type(4))) int i32x4;

union Pk8 { i32x4 i; bf16x8 h; };
union HF4 { _Float16 h[4]; uint2 u; };                      // fp16 quad <-> 8B

__device__ __forceinline__ float relu_f(float x) { return fmaxf(x, 0.0f); }

// scalar bf16 RNE (prep / scalar stores)
__device__ __forceinline__ unsigned short f2bf(float x) {
    unsigned u = __float_as_uint(x);
    u += 0x7FFFu + ((u >> 16) & 1u);
    return (unsigned short)(u >> 16);
}
__device__ __forceinline__ float bf2f(unsigned short h) {
    return __uint_as_float(((unsigned)h) << 16);
}
// packed bf16 pair via v_cvt_pk_bf16_f32 (lo -> low 16 bits)
__device__ __forceinline__ unsigned pk2(float lo, float hi) {
    union { __hip_bfloat162 v; unsigned u; } r;
    r.v = __float22bfloat162_rn(make_float2(lo, hi));
    return r.u;
}
// load 8 bf16 (16B aligned) -> 8 floats
__device__ __forceinline__ void ld8bf(const unsigned short* p, float* o) {
    const i32x4 u = *(const i32x4*)p;
#pragma unroll
    for (int i = 0; i < 4; ++i) {
        o[2 * i]     = bf2f((unsigned short)(u[i] & 0xFFFF));
        o[2 * i + 1] = bf2f((unsigned short)((unsigned)u[i] >> 16));
    }
}

// ---------------------------------------------------------------------------
// Prep: bf16 weight blocks + pre-summed biases.
//  Wcat1[32][192]: k<128 -> we1s; 128..159 -> 0.5*we1p(diff); 160..191 -> 0.5*we1p(sum)
//  Wn1pb[32][128]: wn1p
//  Wcat2[32][96]:  0.5*we2p(diff) | 0.5*we2p(sum) | we2s
// ---------------------------------------------------------------------------
__global__ __launch_bounds__(256) void k_prep(
    const float* __restrict__ we1s, const float* __restrict__ we1p,
    const float* __restrict__ be1p, const float* __restrict__ be1s,
    const float* __restrict__ we2p, const float* __restrict__ we2s,
    const float* __restrict__ be2p, const float* __restrict__ be2s,
    const float* __restrict__ wn1p, const float* __restrict__ bn1p,
    const float* __restrict__ bn1s,
    unsigned short* __restrict__ Wcat1, unsigned short* __restrict__ Wcat2,
    unsigned short* __restrict__ Wn1pb,
    float* __restrict__ bias1, float* __restrict__ bias2,
    float* __restrict__ bias_n1)
{
    const int tid = threadIdx.x;
    for (int idx = tid; idx < 32 * 192; idx += 256) {
        const int n = idx / 192, k = idx - n * 192;
        float w;
        if (k < 128)       w = we1s[n * 128 + k];
        else if (k < 160)  w = 0.5f * we1p[n * 64 + (k - 128)];
        else               w = 0.5f * we1p[n * 64 + 32 + (k - 160)];
        Wcat1[idx] = f2bf(w);
    }
    for (int idx = tid; idx < 32 * 96; idx += 256) {
        const int n = idx / 96, k = idx - n * 96;
        float w;
        if (k < 32)       w = 0.5f * we2p[n * 64 + k];
        else if (k < 64)  w = 0.5f * we2p[n * 64 + 32 + (k - 32)];
        else              w = we2s[n * 32 + (k - 64)];
        Wcat2[idx] = f2bf(w);
    }
    for (int idx = tid; idx < 32 * 128; idx += 256)
        Wn1pb[idx] = f2bf(wn1p[idx]);
    if (tid < H) {
        bias1[tid] = be1p[tid] + be1s[tid];
        bias2[tid] = be2p[tid] + be2s[tid];
        bias_n1[tid] = bn1p[tid] + bn1s[tid];
    }
}

// ---------------------------------------------------------------------------
// P1 (MFMA): one wave = one node = 16 edges. ONE pass over the X gathers.
//   A[e][k] = |X[src]-X[dst]| (128 k's, bf16 frags)
//   t1[e]   = A @ we1s^T    -> fp16, C-layout  (finished by P2)
//   U[e]    = A @ wn1p^T;  Xn1[node] = relu(colsum(U)/D + bias_n1) -> bf16
// All 16 X float4s + all 16 B frags loaded before packing (latency overlap).
// ---------------------------------------------------------------------------
__global__ __launch_bounds__(256) void k_p1(
    const float* __restrict__ X, const int* __restrict__ dst,
    const float* __restrict__ D,
    const unsigned short* __restrict__ Wcat1,
    const unsigned short* __restrict__ Wn1pb,
    const float* __restrict__ bias_n1,
    unsigned short* __restrict__ t1h, unsigned short* __restrict__ Xn1b, int N)
{
    const int wave = threadIdx.x >> 6;
    const int lane = threadIdx.x & 63;
    const int node = blockIdx.x * 4 + wave;
    if (node >= N) return;                  // wave-uniform (grid exact for N%4==0)
    const int m = lane & 15, g = lane >> 4;
    const int e = node * DEG + m;
    const int d = dst[e];
    const float invD = 1.0f / D[node];

    // --- issue ALL global loads up front ---
    const float4* __restrict__ Xs4 = (const float4*)(X + (size_t)node * F_IN);
    const float4* __restrict__ Xd4 = (const float4*)(X + (size_t)d * F_IN);
    float4 sv[8], tv[8];
#pragma unroll
    for (int kb = 0; kb < 4; ++kb) {
        sv[2 * kb]     = Xs4[kb * 8 + g * 2];
        sv[2 * kb + 1] = Xs4[kb * 8 + g * 2 + 1];
        tv[2 * kb]     = Xd4[kb * 8 + g * 2];
        tv[2 * kb + 1] = Xd4[kb * 8 + g * 2 + 1];
    }
    bf16x8 Bs[4][2], Bn[4][2];
#pragma unroll
    for (int kb = 0; kb < 4; ++kb)
#pragma unroll
        for (int t = 0; t < 2; ++t) {
            Bs[kb][t] = *(const bf16x8*)(Wcat1 + (t * 16 + m) * 192 + kb * 32 + g * 8);
            Bn[kb][t] = *(const bf16x8*)(Wn1pb + (t * 16 + m) * 128 + kb * 32 + g * 8);
        }

    f32x4 cs0 = {0.f,0.f,0.f,0.f}, cs1 = {0.f,0.f,0.f,0.f};
    f32x4 cn0 = {0.f,0.f,0.f,0.f}, cn1 = {0.f,0.f,0.f,0.f};
#pragma unroll
    for (int kb = 0; kb < 4; ++kb) {
        const float4 s0 = sv[2 * kb], s1 = sv[2 * kb + 1];
        const float4 t0 = tv[2 * kb], t1 = tv[2 * kb + 1];
        Pk8 a;
        a.i[0] = pk2(fabsf(s0.x - t0.x), fabsf(s0.y - t0.y));
        a.i[1] = pk2(fabsf(s0.z - t0.z), fabsf(s0.w - t0.w));
        a.i[2] = pk2(fabsf(s1.x - t1.x), fabsf(s1.y - t1.y));
        a.i[3] = pk2(fabsf(s1.z - t1.z), fabsf(s1.w - t1.w));
        cs0 = __builtin_amdgcn_mfma_f32_16x16x32_bf16(a.h, Bs[kb][0], cs0, 0, 0, 0);
        cs1 = __builtin_amdgcn_mfma_f32_16x16x32_bf16(a.h, Bs[kb][1], cs1, 0, 0, 0);
        cn0 = __builtin_amdgcn_mfma_f32_16x16x32_bf16(a.h, Bn[kb][0], cn0, 0, 0, 0);
        cn1 = __builtin_amdgcn_mfma_f32_16x16x32_bf16(a.h, Bn[kb][1], cn1, 0, 0, 0);
    }
    // --- t1 store: fp16, C-layout (identity mapping for P2), coalesced 8B/lane ---
    {
        HF4 a;
#pragma unroll
        for (int r = 0; r < 4; ++r) a.h[r] = (_Float16)cs0[r];
        *(uint2*)(t1h + (size_t)node * 512 + lane * 4) = a.u;
#pragma unroll
        for (int r = 0; r < 4; ++r) a.h[r] = (_Float16)cs1[r];
        *(uint2*)(t1h + (size_t)node * 512 + 256 + lane * 4) = a.u;
    }
    // --- Xn1: column sums of U over 16 edges ---
    float un0 = cn0[0] + cn0[1] + cn0[2] + cn0[3];
    float un1 = cn1[0] + cn1[1] + cn1[2] + cn1[3];
    un0 += __shfl_xor(un0, 16); un0 += __shfl_xor(un0, 32);
    un1 += __shfl_xor(un1, 16); un1 += __shfl_xor(un1, 32);
    if (g == 0) {
        Xn1b[(size_t)node * H + m]      = f2bf(relu_f(un0 * invD + bias_n1[m]));
        Xn1b[(size_t)node * H + 16 + m] = f2bf(relu_f(un1 * invD + bias_n1[16 + m]));
    }
}

// ---------------------------------------------------------------------------
// P2 (MFMA): finish edge_conv1. C init = t1 (fp16); add Ef1 @ we1p (folded).
//   vals1 = relu(C + bias1)  -> bf16 row-major, IN PLACE over t1 buffer
//   Asum[node] = col-sum of vals1 over the node's 16 edges (fp32)
// Row-major repack via per-wave LDS region (stride 40 ushorts, <=2-way banks).
// ---------------------------------------------------------------------------
__global__ __launch_bounds__(256) void k_p2(
    const int* __restrict__ dst, const unsigned short* __restrict__ Xn1b,
    const unsigned short* __restrict__ Wcat1, const float* __restrict__ bias1,
    unsigned short* t1v1,          // no restrict: read t1h + write vals1 (same buf)
    float* __restrict__ Asum, int N)
{
    __shared__ unsigned short lds[4][16 * 40];
    const int wave = threadIdx.x >> 6;
    const int lane = threadIdx.x & 63;
    const int node = blockIdx.x * 4 + wave;
    if (node >= N) return;                  // wave-uniform; LDS is per-wave (no barrier)
    const int m = lane & 15, g = lane >> 4;
    const int e = node * DEG + m;
    const int d = dst[e];

    // loads up front
    float x1v[8], x2v[8];
    ld8bf(Xn1b + (size_t)node * H + g * 8, x1v);
    ld8bf(Xn1b + (size_t)d * H + g * 8, x2v);
    uint2 u0 = *(const uint2*)(t1v1 + (size_t)node * 512 + lane * 4);
    uint2 u1 = *(const uint2*)(t1v1 + (size_t)node * 512 + 256 + lane * 4);
    bf16x8 Bf[2][2];
#pragma unroll
    for (int kb = 0; kb < 2; ++kb)
#pragma unroll
        for (int t = 0; t < 2; ++t)
            Bf[kb][t] = *(const bf16x8*)(Wcat1 + (t * 16 + m) * 192 + (4 + kb) * 32 + g * 8);

    f32x4 c0, c1;
    { HF4 a; a.u = u0;
#pragma unroll
      for (int r = 0; r < 4; ++r) c0[r] = (float)a.h[r];
      a.u = u1;
#pragma unroll
      for (int r = 0; r < 4; ++r) c1[r] = (float)a.h[r]; }

    Pk8 ad, aS;
#pragma unroll
    for (int i = 0; i < 4; ++i) {
        ad.i[i] = pk2(x1v[2 * i] - x2v[2 * i], x1v[2 * i + 1] - x2v[2 * i + 1]);
        aS.i[i] = pk2(x1v[2 * i] + x2v[2 * i], x1v[2 * i + 1] + x2v[2 * i + 1]);
    }
    c0 = __builtin_amdgcn_mfma_f32_16x16x32_bf16(ad.h, Bf[0][0], c0, 0, 0, 0);
    c1 = __builtin_amdgcn_mfma_f32_16x16x32_bf16(ad.h, Bf[0][1], c1, 0, 0, 0);
    c0 = __builtin_amdgcn_mfma_f32_16x16x32_bf16(aS.h, Bf[1][0], c0, 0, 0, 0);
    c1 = __builtin_amdgcn_mfma_f32_16x16x32_bf16(aS.h, Bf[1][1], c1, 0, 0, 0);

    const float b0 = bias1[m], b1v = bias1[16 + m];
    float sum0 = 0.f, sum1 = 0.f;
    unsigned short* L = lds[wave];
#pragma unroll
    for (int r = 0; r < 4; ++r) {
        const float v0 = relu_f(c0[r] + b0);
        const float v1 = relu_f(c1[r] + b1v);
        const int row = g * 4 + r;
        L[row * 40 + m]      = f2bf(v0);
        L[row * 40 + 16 + m] = f2bf(v1);
        sum0 += v0; sum1 += v1;
    }
    // repack: lane -> (row = lane>>2, chunk = lane&3), 16B reads (80B row stride)
    {
        const int row = lane >> 2, chunk = lane & 3;
        const i32x4 v = *(const i32x4*)(L + row * 40 + chunk * 8);
        *(i32x4*)(t1v1 + ((size_t)node * DEG + row) * H + chunk * 8) = v;
    }
    sum0 += __shfl_xor(sum0, 16); sum0 += __shfl_xor(sum0, 32);
    sum1 += __shfl_xor(sum1, 16); sum1 += __shfl_xor(sum1, 32);
    if (g == 0) {
        Asum[(size_t)node * H + m] = sum0;
        Asum[(size_t)node * H + 16 + m] = sum1;
    }
}

// ---------------------------------------------------------------------------
// Xn2 = relu((Asum/D)@wn2p^T + Xn1@wn2s^T + bn2p + bn2s) -> bf16 (proven)
// ---------------------------------------------------------------------------
__global__ __launch_bounds__(256) void k_xn2(
    const unsigned short* __restrict__ Xn1b, const float* __restrict__ Asum,
    const float* __restrict__ D,
    const float* __restrict__ wn2p, const float* __restrict__ bn2p,
    const float* __restrict__ wn2s, const float* __restrict__ bn2s,
    unsigned short* __restrict__ Xn2b, int N)
{
    __shared__ float Wp[H * H], Wsl[H * H], b2s[H];
    __shared__ float As[8 * H], Xl[8 * H];
    const int tid = threadIdx.x;
#pragma unroll
    for (int r = 0; r < 4; ++r) {
        const int idx = r * 256 + tid;
        Wp[idx] = wn2p[idx];
        Wsl[idx] = wn2s[idx];
    }
    if (tid < H) b2s[tid] = bn2p[tid] + bn2s[tid];
    {
        const int nl = tid >> 5, k = tid & 31;
        int node = blockIdx.x * 8 + nl;
        if (node >= N) node = N - 1;
        As[tid] = Asum[(size_t)node * H + k] * (1.0f / D[node]);
        Xl[tid] = bf2f(Xn1b[(size_t)node * H + k]);
    }
    __syncthreads();
    const int nl = tid >> 5, o = tid & 31;
    const int node = blockIdx.x * 8 + nl;
    if (node < N) {
        float a = b2s[o];
        const float4* wp4 = (const float4*)(Wp + o * H);
        const float4* ws4 = (const float4*)(Wsl + o * H);
        const float4* av = (const float4*)(As + nl * H);
        const float4* xv = (const float4*)(Xl + nl * H);
#pragma unroll
        for (int k4 = 0; k4 < 8; ++k4) {
            const float4 w = wp4[k4], v = av[k4];
            a += v.x * w.x + v.y * w.y + v.z * w.z + v.w * w.w;
            const float4 w2 = ws4[k4], x = xv[k4];
            a += x.x * w2.x + x.y * w2.y + x.z * w2.z + x.w * w2.w;
        }
        Xn2b[(size_t)node * H + o] = f2bf(relu_f(a));
    }
}

// ---------------------------------------------------------------------------
// P3 (MFMA, proven in R4): layer-2 edge conv + classifier + sigmoid.
// ---------------------------------------------------------------------------
__global__ __launch_bounds__(256) void k_p3(
    const unsigned short* __restrict__ Xn2b, const int* __restrict__ dst,
    const unsigned short* __restrict__ vals1,
    const unsigned short* __restrict__ Wcat2, const float* __restrict__ bias2,
    const float* __restrict__ wc, const float* __restrict__ bc,
    float* __restrict__ out, int N)
{
    const int wave = threadIdx.x >> 6;
    const int lane = threadIdx.x & 63;
    const int node = blockIdx.x * 4 + wave;
    if (node >= N) return;                 // wave-uniform
    const int m = lane & 15, g = lane >> 4;
    const int e = node * DEG + m;
    const int d = dst[e];

    // loads up front
    float x1v[8], x2v[8];
    ld8bf(Xn2b + (size_t)node * H + g * 8, x1v);
    ld8bf(Xn2b + (size_t)d * H + g * 8, x2v);
    const bf16x8 av = *(const bf16x8*)(vals1 + (size_t)e * H + g * 8);
    bf16x8 Bf[3][2];
#pragma unroll
    for (int kb = 0; kb < 3; ++kb)
#pragma unroll
        for (int t = 0; t < 2; ++t)
            Bf[kb][t] = *(const bf16x8*)(Wcat2 + (t * 16 + m) * 96 + kb * 32 + g * 8);

    f32x4 c0 = {0.f,0.f,0.f,0.f}, c1 = {0.f,0.f,0.f,0.f};
    Pk8 ad, aS;
#pragma unroll
    for (int i = 0; i < 4; ++i) {
        ad.i[i] = pk2(x1v[2 * i] - x2v[2 * i], x1v[2 * i + 1] - x2v[2 * i + 1]);
        aS.i[i] = pk2(x1v[2 * i] + x2v[2 * i], x1v[2 * i + 1] + x2v[2 * i + 1]);
    }
    c0 = __builtin_amdgcn_mfma_f32_16x16x32_bf16(ad.h, Bf[0][0], c0, 0, 0, 0);
    c1 = __builtin_amdgcn_mfma_f32_16x16x32_bf16(ad.h, Bf[0][1], c1, 0, 0, 0);
    c0 = __builtin_amdgcn_mfma_f32_16x16x32_bf16(aS.h, Bf[1][0], c0, 0, 0, 0);
    c1 = __builtin_amdgcn_mfma_f32_16x16x32_bf16(aS.h, Bf[1][1], c1, 0, 0, 0);
    c0 = __builtin_amdgcn_mfma_f32_16x16x32_bf16(av,   Bf[2][0], c0, 0, 0, 0);
    c1 = __builtin_amdgcn_mfma_f32_16x16x32_bf16(av,   Bf[2][1], c1, 0, 0, 0);

    const float b0 = bias2[m], b1v = bias2[16 + m];
    const float w0 = wc[m], w1 = wc[16 + m];
    float sr[4];
#pragma unroll
    for (int r = 0; r < 4; ++r)
        sr[r] = relu_f(c0[r] + b0) * w0 + relu_f(c1[r] + b1v) * w1;
#pragma unroll
    for (int mask = 1; mask < 16; mask <<= 1) {
#pragma unroll
        for (int r = 0; r < 4; ++r)
            sr[r] += __shfl_xor(sr[r], mask);
    }
    if (m == 0) {
        const float bb = bc[0];
        float4 o4;
        o4.x = 1.0f / (1.0f + __expf(-(sr[0] + bb)));
        o4.y = 1.0f / (1.0f + __expf(-(sr[1] + bb)));
        o4.z = 1.0f / (1.0f + __expf(-(sr[2] + bb)));
        o4.w = 1.0f / (1.0f + __expf(-(sr[3] + bb)));
        *(float4*)(out + node * DEG + g * 4) = o4;
    }
}

// ---------------------------------------------------------------------------
extern "C" void kernel_launch(void* const* d_in, const int* in_sizes, int n_in,
                              void* d_out, int out_size, void* d_ws, size_t ws_size,
                              hipStream_t stream)
{
    const float* X    = (const float*)d_in[0];
    const int*   dst  = (const int*)  d_in[2];
    const float* D    = (const float*)d_in[3];
    const float* wn1p = (const float*)d_in[4];
    const float* bn1p = (const float*)d_in[5];
    // d_in[6] = wn1s unused: X0 == zeros, self term reduces to bn1s.
    const float* bn1s = (const float*)d_in[7];
    const float* we1p = (const float*)d_in[8];
    const float* be1p = (const float*)d_in[9];
    const float* we1s = (const float*)d_in[10];
    const float* be1s = (const float*)d_in[11];
    const float* wn2p = (const float*)d_in[12];
    const float* bn2p = (const float*)d_in[13];
    const float* wn2s = (const float*)d_in[14];
    const float* bn2s = (const float*)d_in[15];
    const float* we2p = (const float*)d_in[16];
    const float* be2p = (const float*)d_in[17];
    const float* we2s = (const float*)d_in[18];
    const float* be2s = (const float*)d_in[19];
    const float* wc   = (const float*)d_in[20];
    const float* bc   = (const float*)d_in[21];

    const int N = in_sizes[3];   // D has one entry per node
    const size_t E = (size_t)N * DEG;

    // ws (~64.1 MB, same proven footprint):
    char* w = (char*)d_ws;
    unsigned short* t1v1  = (unsigned short*)w;  w += E * H * 2;          // t1(fp16)/vals1(bf16), 51.2 MB
    unsigned short* Xn1b  = (unsigned short*)w;  w += (size_t)N * H * 2;  // 3.2 MB
    unsigned short* Xn2b  = (unsigned short*)w;  w += (size_t)N * H * 2;  // 3.2 MB
    float*          AsumP = (float*)w;           w += (size_t)N * H * 4;  // 6.4 MB
    unsigned short* Wcat1 = (unsigned short*)w;  w += 32 * 192 * 2;
    unsigned short* Wcat2 = (unsigned short*)w;  w += 32 * 96 * 2;
    unsigned short* Wn1pb = (unsigned short*)w;  w += 32 * 128 * 2;
    float*          bias1 = (float*)w;           w += H * 4;
    float*          bias2 = (float*)w;           w += H * 4;
    float*          biasn1= (float*)w;           w += H * 4;
    float* outp = (float*)d_out;

    const int nb4 = (N + 3) / 4;
    const int nb8 = (N + 7) / 8;

    k_prep<<<1, 256, 0, stream>>>(we1s, we1p, be1p, be1s, we2p, we2s, be2p, be2s,
                                  wn1p, bn1p, bn1s,
                                  Wcat1, Wcat2, Wn1pb, bias1, bias2, biasn1);
    k_p1<<<nb4, 256, 0, stream>>>(X, dst, D, Wcat1, Wn1pb, biasn1, t1v1, Xn1b, N);
    k_p2<<<nb4, 256, 0, stream>>>(dst, Xn1b, Wcat1, bias1, t1v1, AsumP, N);
    k_xn2<<<nb8, 256, 0, stream>>>(Xn1b, AsumP, D, wn2p, bn2p, wn2s, bn2s, Xn2b, N);
    k_p3<<<nb4, 256, 0, stream>>>(Xn2b, dst, t1v1, Wcat2, bias2, wc, bc, outp, N);
}

// Round 6
// 285.938 us; speedup vs baseline: 2.6333x; 1.2517x over previous
//
#include <hip/hip_runtime.h>
#include <hip/hip_bf16.h>

#define DEG 16
#define F_IN 128
#define H 32
#define CH 16   // nodes per chunk (= per block)

typedef __attribute__((ext_vector_type(8))) short bf16x8;   // 8 bf16 = 4 VGPRs (MFMA A/B frag)
typedef __attribute__((ext_vector_type(4))) float f32x4;    // MFMA C/D frag
typedef __attribute__((ext_vector_type(4))) int i32x4;

union Pk8 { i32x4 i; bf16x8 h; };
union HF4 { _Float16 h[4]; uint2 u; };                      // fp16 quad <-> 8B

__device__ __forceinline__ float relu_f(float x) { return fmaxf(x, 0.0f); }

__device__ __forceinline__ unsigned short f2bf(float x) {
    unsigned u = __float_as_uint(x);
    u += 0x7FFFu + ((u >> 16) & 1u);
    return (unsigned short)(u >> 16);
}
__device__ __forceinline__ float bf2f(unsigned short h) {
    return __uint_as_float(((unsigned)h) << 16);
}
// packed bf16 pair via v_cvt_pk_bf16_f32 (lo -> low 16 bits)
__device__ __forceinline__ unsigned pk2(float lo, float hi) {
    union { __hip_bfloat162 v; unsigned u; } r;
    r.v = __float22bfloat162_rn(make_float2(lo, hi));
    return r.u;
}
// load 8 bf16 (16B aligned) -> 8 floats
__device__ __forceinline__ void ld8bf(const unsigned short* p, float* o) {
    const i32x4 u = *(const i32x4*)p;
#pragma unroll
    for (int i = 0; i < 4; ++i) {
        o[2 * i]     = bf2f((unsigned short)(u[i] & 0xFFFF));
        o[2 * i + 1] = bf2f((unsigned short)((unsigned)u[i] >> 16));
    }
}

// ---------------------------------------------------------------------------
// Prep: bf16 weight blocks + pre-summed biases (unchanged from R5).
// ---------------------------------------------------------------------------
__global__ __launch_bounds__(256) void k_prep(
    const float* __restrict__ we1s, const float* __restrict__ we1p,
    const float* __restrict__ be1p, const float* __restrict__ be1s,
    const float* __restrict__ we2p, const float* __restrict__ we2s,
    const float* __restrict__ be2p, const float* __restrict__ be2s,
    const float* __restrict__ wn1p, const float* __restrict__ bn1p,
    const float* __restrict__ bn1s,
    unsigned short* __restrict__ Wcat1, unsigned short* __restrict__ Wcat2,
    unsigned short* __restrict__ Wn1pb,
    float* __restrict__ bias1, float* __restrict__ bias2,
    float* __restrict__ bias_n1)
{
    const int tid = threadIdx.x;
    for (int idx = tid; idx < 32 * 192; idx += 256) {
        const int n = idx / 192, k = idx - n * 192;
        float w;
        if (k < 128)       w = we1s[n * 128 + k];
        else if (k < 160)  w = 0.5f * we1p[n * 64 + (k - 128)];
        else               w = 0.5f * we1p[n * 64 + 32 + (k - 160)];
        Wcat1[idx] = f2bf(w);
    }
    for (int idx = tid; idx < 32 * 96; idx += 256) {
        const int n = idx / 96, k = idx - n * 96;
        float w;
        if (k < 32)       w = 0.5f * we2p[n * 64 + k];
        else if (k < 64)  w = 0.5f * we2p[n * 64 + 32 + (k - 32)];
        else              w = we2s[n * 32 + (k - 64)];
        Wcat2[idx] = f2bf(w);
    }
    for (int idx = tid; idx < 32 * 128; idx += 256)
        Wn1pb[idx] = f2bf(wn1p[idx]);
    if (tid < H) {
        bias1[tid] = be1p[tid] + be1s[tid];
        bias2[tid] = be2p[tid] + be2s[tid];
        bias_n1[tid] = bn1p[tid] + bn1s[tid];
    }
}

// ---------------------------------------------------------------------------
// P1: block = 16-node chunk; wave handles 4 tiles (16 consecutive nodes x one
// offset j). All gathers are contiguous streams (circulant graph).
//   t1 tile  = |X[src]-X[dst]| @ we1s^T  -> fp16 C-layout, per tile
//   U accum  = |ΔX| @ wn1p^T, accumulated over the wave's 4 j's in AGPRs,
//              cross-wave LDS reduce -> Xn1 = relu(U/D + bias)
// ---------------------------------------------------------------------------
__global__ __launch_bounds__(256) void k_p1(
    const float* __restrict__ X, const int* __restrict__ dst,
    const float* __restrict__ D,
    const unsigned short* __restrict__ Wcat1,
    const unsigned short* __restrict__ Wn1pb,
    const float* __restrict__ bias_n1,
    unsigned short* __restrict__ t1h, unsigned short* __restrict__ Xn1b, int N)
{
    __shared__ int dsL[16 * 17];
    __shared__ float UacS[4][16 * 33];
    const int tid = threadIdx.x;
    const int wave = tid >> 6, lane = tid & 63;
    const int i0 = blockIdx.x * CH;
    {
        const int mm = tid >> 4, j = tid & 15;
        const int nd = (i0 + mm < N) ? (i0 + mm) : (N - 1);
        dsL[mm * 17 + j] = dst[nd * DEG + j];
    }
    __syncthreads();
    const int m = lane & 15, g = lane >> 4;
    const int srow = (i0 + m < N) ? (i0 + m) : (N - 1);

    // src rows (16 consecutive rows, streamed), shared across the 4 j-tiles
    const float4* __restrict__ Xs4 = (const float4*)(X + (size_t)srow * F_IN);
    float4 sv[8];
#pragma unroll
    for (int kb = 0; kb < 4; ++kb) {
        sv[2 * kb]     = Xs4[kb * 8 + g * 2];
        sv[2 * kb + 1] = Xs4[kb * 8 + g * 2 + 1];
    }
    bf16x8 Bs[4][2], Bn[4][2];
#pragma unroll
    for (int kb = 0; kb < 4; ++kb)
#pragma unroll
        for (int t = 0; t < 2; ++t) {
            Bs[kb][t] = *(const bf16x8*)(Wcat1 + (t * 16 + m) * 192 + kb * 32 + g * 8);
            Bn[kb][t] = *(const bf16x8*)(Wn1pb + (t * 16 + m) * 128 + kb * 32 + g * 8);
        }

    f32x4 cn0 = {0.f,0.f,0.f,0.f}, cn1 = {0.f,0.f,0.f,0.f};   // U, accumulated over jj
#pragma unroll
    for (int jj = 0; jj < 4; ++jj) {
        const int j = wave * 4 + jj;
        const int d = dsL[m * 17 + j];
        const float4* __restrict__ Xd4 = (const float4*)(X + (size_t)d * F_IN);
        float4 tv[8];
#pragma unroll
        for (int kb = 0; kb < 4; ++kb) {
            tv[2 * kb]     = Xd4[kb * 8 + g * 2];
            tv[2 * kb + 1] = Xd4[kb * 8 + g * 2 + 1];
        }
        f32x4 cs0 = {0.f,0.f,0.f,0.f}, cs1 = {0.f,0.f,0.f,0.f};
#pragma unroll
        for (int kb = 0; kb < 4; ++kb) {
            const float4 s0 = sv[2 * kb], s1 = sv[2 * kb + 1];
            const float4 t0 = tv[2 * kb], t1 = tv[2 * kb + 1];
            Pk8 a;
            a.i[0] = pk2(fabsf(s0.x - t0.x), fabsf(s0.y - t0.y));
            a.i[1] = pk2(fabsf(s0.z - t0.z), fabsf(s0.w - t0.w));
            a.i[2] = pk2(fabsf(s1.x - t1.x), fabsf(s1.y - t1.y));
            a.i[3] = pk2(fabsf(s1.z - t1.z), fabsf(s1.w - t1.w));
            cs0 = __builtin_amdgcn_mfma_f32_16x16x32_bf16(a.h, Bs[kb][0], cs0, 0, 0, 0);
            cs1 = __builtin_amdgcn_mfma_f32_16x16x32_bf16(a.h, Bs[kb][1], cs1, 0, 0, 0);
            cn0 = __builtin_amdgcn_mfma_f32_16x16x32_bf16(a.h, Bn[kb][0], cn0, 0, 0, 0);
            cn1 = __builtin_amdgcn_mfma_f32_16x16x32_bf16(a.h, Bn[kb][1], cn1, 0, 0, 0);
        }
        // t1 tile store: fp16 C-layout, 8B/lane coalesced
        const size_t tb = ((size_t)blockIdx.x * 16 + j) * 512;
        HF4 a;
#pragma unroll
        for (int r = 0; r < 4; ++r) a.h[r] = (_Float16)cs0[r];
        *(uint2*)(t1h + tb + lane * 4) = a.u;
#pragma unroll
        for (int r = 0; r < 4; ++r) a.h[r] = (_Float16)cs1[r];
        *(uint2*)(t1h + tb + 256 + lane * 4) = a.u;
    }
    // cross-wave reduce of U -> Xn1   (C layout: col=lane&15=n, row=g*4+r=node)
#pragma unroll
    for (int r = 0; r < 4; ++r) {
        UacS[wave][(g * 4 + r) * 33 + m]      = cn0[r];
        UacS[wave][(g * 4 + r) * 33 + 16 + m] = cn1[r];
    }
    __syncthreads();
    {
        const int mm = tid >> 4, c = tid & 15;
        float u0 = 0.f, u1 = 0.f;
#pragma unroll
        for (int w = 0; w < 4; ++w) {
            u0 += UacS[w][mm * 33 + c];
            u1 += UacS[w][mm * 33 + 16 + c];
        }
        if (i0 + mm < N) {
            const float invD = 1.0f / D[i0 + mm];
            Xn1b[(size_t)(i0 + mm) * H + c]      = f2bf(relu_f(u0 * invD + bias_n1[c]));
            Xn1b[(size_t)(i0 + mm) * H + 16 + c] = f2bf(relu_f(u1 * invD + bias_n1[16 + c]));
        }
    }
}

// ---------------------------------------------------------------------------
// P2: finish edge_conv1 per tile (C init = t1 fp16; + Ef1 @ folded we1p).
//   vals1 tile -> bf16 TILE-MAJOR [tile][m][n], in place over t1 buffer.
//   Asum[node] = Σ_j vals1 accumulated in registers + cross-wave LDS reduce.
// ---------------------------------------------------------------------------
__global__ __launch_bounds__(256) void k_p2(
    const int* __restrict__ dst, const unsigned short* __restrict__ Xn1b,
    const unsigned short* __restrict__ Wcat1, const float* __restrict__ bias1,
    unsigned short* t1v1,          // read t1 fp16, write vals1 bf16 (same buf)
    float* __restrict__ Asum, int N)
{
    __shared__ int dsL[16 * 17];
    __shared__ unsigned short RP[4][16 * 40];
    __shared__ float AacS[4][16 * 33];
    const int tid = threadIdx.x;
    const int wave = tid >> 6, lane = tid & 63;
    const int i0 = blockIdx.x * CH;
    {
        const int mm = tid >> 4, j = tid & 15;
        const int nd = (i0 + mm < N) ? (i0 + mm) : (N - 1);
        dsL[mm * 17 + j] = dst[nd * DEG + j];
    }
    __syncthreads();
    const int m = lane & 15, g = lane >> 4;
    const int srow = (i0 + m < N) ? (i0 + m) : (N - 1);

    float x1v[8];
    ld8bf(Xn1b + (size_t)srow * H + g * 8, x1v);
    bf16x8 Bf[2][2];
#pragma unroll
    for (int kb = 0; kb < 2; ++kb)
#pragma unroll
        for (int t = 0; t < 2; ++t)
            Bf[kb][t] = *(const bf16x8*)(Wcat1 + (t * 16 + m) * 192 + (4 + kb) * 32 + g * 8);

    const float b0 = bias1[m], b1v = bias1[16 + m];
    float sA0[4] = {0.f,0.f,0.f,0.f}, sA1[4] = {0.f,0.f,0.f,0.f};
    unsigned short* L = RP[wave];
#pragma unroll
    for (int jj = 0; jj < 4; ++jj) {
        const int j = wave * 4 + jj;
        const int d = dsL[m * 17 + j];
        float x2v[8];
        ld8bf(Xn1b + (size_t)d * H + g * 8, x2v);
        const size_t tb = ((size_t)blockIdx.x * 16 + j) * 512;
        const uint2 u0 = *(const uint2*)(t1v1 + tb + lane * 4);
        const uint2 u1 = *(const uint2*)(t1v1 + tb + 256 + lane * 4);
        f32x4 c0, c1;
        { HF4 a; a.u = u0;
#pragma unroll
          for (int r = 0; r < 4; ++r) c0[r] = (float)a.h[r];
          a.u = u1;
#pragma unroll
          for (int r = 0; r < 4; ++r) c1[r] = (float)a.h[r]; }
        Pk8 ad, aS;
#pragma unroll
        for (int i = 0; i < 4; ++i) {
            ad.i[i] = pk2(x1v[2 * i] - x2v[2 * i], x1v[2 * i + 1] - x2v[2 * i + 1]);
            aS.i[i] = pk2(x1v[2 * i] + x2v[2 * i], x1v[2 * i + 1] + x2v[2 * i + 1]);
        }
        c0 = __builtin_amdgcn_mfma_f32_16x16x32_bf16(ad.h, Bf[0][0], c0, 0, 0, 0);
        c1 = __builtin_amdgcn_mfma_f32_16x16x32_bf16(ad.h, Bf[0][1], c1, 0, 0, 0);
        c0 = __builtin_amdgcn_mfma_f32_16x16x32_bf16(aS.h, Bf[1][0], c0, 0, 0, 0);
        c1 = __builtin_amdgcn_mfma_f32_16x16x32_bf16(aS.h, Bf[1][1], c1, 0, 0, 0);
#pragma unroll
        for (int r = 0; r < 4; ++r) {
            const float v0 = relu_f(c0[r] + b0);
            const float v1 = relu_f(c1[r] + b1v);
            L[(g * 4 + r) * 40 + m]      = f2bf(v0);
            L[(g * 4 + r) * 40 + 16 + m] = f2bf(v1);
            sA0[r] += v0; sA1[r] += v1;
        }
        // repack to tile-major bf16, dense 16B stores (in place over t1)
        const int rr = lane >> 2, q = lane & 3;
        const i32x4 v = *(const i32x4*)(L + rr * 40 + q * 8);
        *(i32x4*)(t1v1 + tb + rr * 32 + q * 8) = v;
    }
#pragma unroll
    for (int r = 0; r < 4; ++r) {
        AacS[wave][(g * 4 + r) * 33 + m]      = sA0[r];
        AacS[wave][(g * 4 + r) * 33 + 16 + m] = sA1[r];
    }
    __syncthreads();
    {
        const int mm = tid >> 4, c = tid & 15;
        float a0 = 0.f, a1 = 0.f;
#pragma unroll
        for (int w = 0; w < 4; ++w) {
            a0 += AacS[w][mm * 33 + c];
            a1 += AacS[w][mm * 33 + 16 + c];
        }
        if (i0 + mm < N) {
            Asum[(size_t)(i0 + mm) * H + c]      = a0;
            Asum[(size_t)(i0 + mm) * H + 16 + c] = a1;
        }
    }
}

// ---------------------------------------------------------------------------
// Xn2 = relu((Asum/D)@wn2p^T + Xn1@wn2s^T + bn2p + bn2s) -> bf16 (proven)
// ---------------------------------------------------------------------------
__global__ __launch_bounds__(256) void k_xn2(
    const unsigned short* __restrict__ Xn1b, const float* __restrict__ Asum,
    const float* __restrict__ D,
    const float* __restrict__ wn2p, const float* __restrict__ bn2p,
    const float* __restrict__ wn2s, const float* __restrict__ bn2s,
    unsigned short* __restrict__ Xn2b, int N)
{
    __shared__ float Wp[H * H], Wsl[H * H], b2s[H];
    __shared__ float As[8 * H], Xl[8 * H];
    const int tid = threadIdx.x;
#pragma unroll
    for (int r = 0; r < 4; ++r) {
        const int idx = r * 256 + tid;
        Wp[idx] = wn2p[idx];
        Wsl[idx] = wn2s[idx];
    }
    if (tid < H) b2s[tid] = bn2p[tid] + bn2s[tid];
    {
        const int nl = tid >> 5, k = tid & 31;
        int node = blockIdx.x * 8 + nl;
        if (node >= N) node = N - 1;
        As[tid] = Asum[(size_t)node * H + k] * (1.0f / D[node]);
        Xl[tid] = bf2f(Xn1b[(size_t)node * H + k]);
    }
    __syncthreads();
    const int nl = tid >> 5, o = tid & 31;
    const int node = blockIdx.x * 8 + nl;
    if (node < N) {
        float a = b2s[o];
        const float4* wp4 = (const float4*)(Wp + o * H);
        const float4* ws4 = (const float4*)(Wsl + o * H);
        const float4* av = (const float4*)(As + nl * H);
        const float4* xv = (const float4*)(Xl + nl * H);
#pragma unroll
        for (int k4 = 0; k4 < 8; ++k4) {
            const float4 w = wp4[k4], v = av[k4];
            a += v.x * w.x + v.y * w.y + v.z * w.z + v.w * w.w;
            const float4 w2 = ws4[k4], x = xv[k4];
            a += x.x * w2.x + x.y * w2.y + x.z * w2.z + x.w * w2.w;
        }
        Xn2b[(size_t)node * H + o] = f2bf(relu_f(a));
    }
}

// ---------------------------------------------------------------------------
// P3: layer-2 edge conv + classifier + sigmoid, chunk/j tiling, all streaming.
// out staged in LDS, written as 256 consecutive floats per block.
// ---------------------------------------------------------------------------
__global__ __launch_bounds__(256) void k_p3(
    const unsigned short* __restrict__ Xn2b, const int* __restrict__ dst,
    const unsigned short* __restrict__ vals1,
    const unsigned short* __restrict__ Wcat2, const float* __restrict__ bias2,
    const float* __restrict__ wc, const float* __restrict__ bc,
    float* __restrict__ out, int N)
{
    __shared__ int dsL[16 * 17];
    __shared__ float outS[16 * 17];
    const int tid = threadIdx.x;
    const int wave = tid >> 6, lane = tid & 63;
    const int i0 = blockIdx.x * CH;
    {
        const int mm = tid >> 4, j = tid & 15;
        const int nd = (i0 + mm < N) ? (i0 + mm) : (N - 1);
        dsL[mm * 17 + j] = dst[nd * DEG + j];
    }
    __syncthreads();
    const int m = lane & 15, g = lane >> 4;
    const int srow = (i0 + m < N) ? (i0 + m) : (N - 1);

    float x1v[8];
    ld8bf(Xn2b + (size_t)srow * H + g * 8, x1v);
    bf16x8 Bf[3][2];
#pragma unroll
    for (int kb = 0; kb < 3; ++kb)
#pragma unroll
        for (int t = 0; t < 2; ++t)
            Bf[kb][t] = *(const bf16x8*)(Wcat2 + (t * 16 + m) * 96 + kb * 32 + g * 8);

    const float b0 = bias2[m], b1v = bias2[16 + m];
    const float w0 = wc[m], w1 = wc[16 + m];
#pragma unroll
    for (int jj = 0; jj < 4; ++jj) {
        const int j = wave * 4 + jj;
        const int d = dsL[m * 17 + j];
        float x2v[8];
        ld8bf(Xn2b + (size_t)d * H + g * 8, x2v);
        const size_t tb = ((size_t)blockIdx.x * 16 + j) * 512;
        const bf16x8 av = *(const bf16x8*)(vals1 + tb + m * 32 + g * 8);

        f32x4 c0 = {0.f,0.f,0.f,0.f}, c1 = {0.f,0.f,0.f,0.f};
        Pk8 ad, aS;
#pragma unroll
        for (int i = 0; i < 4; ++i) {
            ad.i[i] = pk2(x1v[2 * i] - x2v[2 * i], x1v[2 * i + 1] - x2v[2 * i + 1]);
            aS.i[i] = pk2(x1v[2 * i] + x2v[2 * i], x1v[2 * i + 1] + x2v[2 * i + 1]);
        }
        c0 = __builtin_amdgcn_mfma_f32_16x16x32_bf16(ad.h, Bf[0][0], c0, 0, 0, 0);
        c1 = __builtin_amdgcn_mfma_f32_16x16x32_bf16(ad.h, Bf[0][1], c1, 0, 0, 0);
        c0 = __builtin_amdgcn_mfma_f32_16x16x32_bf16(aS.h, Bf[1][0], c0, 0, 0, 0);
        c1 = __builtin_amdgcn_mfma_f32_16x16x32_bf16(aS.h, Bf[1][1], c1, 0, 0, 0);
        c0 = __builtin_amdgcn_mfma_f32_16x16x32_bf16(av,   Bf[2][0], c0, 0, 0, 0);
        c1 = __builtin_amdgcn_mfma_f32_16x16x32_bf16(av,   Bf[2][1], c1, 0, 0, 0);

        float sr[4];
#pragma unroll
        for (int r = 0; r < 4; ++r)
            sr[r] = relu_f(c0[r] + b0) * w0 + relu_f(c1[r] + b1v) * w1;
#pragma unroll
        for (int mask = 1; mask < 16; mask <<= 1) {
#pragma unroll
            for (int r = 0; r < 4; ++r)
                sr[r] += __shfl_xor(sr[r], mask);
        }
        if (m == 0) {
#pragma unroll
            for (int r = 0; r < 4; ++r)
                outS[(g * 4 + r) * 17 + j] = sr[r];
        }
    }
    __syncthreads();
    {
        const int mm = tid >> 4, j = tid & 15;
        if (i0 + mm < N) {
            const float sx = outS[mm * 17 + j] + bc[0];
            out[(size_t)i0 * DEG + tid] = 1.0f / (1.0f + __expf(-sx));
        }
    }
}

// ---------------------------------------------------------------------------
extern "C" void kernel_launch(void* const* d_in, const int* in_sizes, int n_in,
                              void* d_out, int out_size, void* d_ws, size_t ws_size,
                              hipStream_t stream)
{
    const float* X    = (const float*)d_in[0];
    const int*   dst  = (const int*)  d_in[2];
    const float* D    = (const float*)d_in[3];
    const float* wn1p = (const float*)d_in[4];
    const float* bn1p = (const float*)d_in[5];
    // d_in[6] = wn1s unused: X0 == zeros, self term reduces to bn1s.
    const float* bn1s = (const float*)d_in[7];
    const float* we1p = (const float*)d_in[8];
    const float* be1p = (const float*)d_in[9];
    const float* we1s = (const float*)d_in[10];
    const float* be1s = (const float*)d_in[11];
    const float* wn2p = (const float*)d_in[12];
    const float* bn2p = (const float*)d_in[13];
    const float* wn2s = (const float*)d_in[14];
    const float* bn2s = (const float*)d_in[15];
    const float* we2p = (const float*)d_in[16];
    const float* be2p = (const float*)d_in[17];
    const float* we2s = (const float*)d_in[18];
    const float* be2s = (const float*)d_in[19];
    const float* wc   = (const float*)d_in[20];
    const float* bc   = (const float*)d_in[21];

    const int N = in_sizes[3];        // D has one entry per node
    const int nbC = (N + CH - 1) / CH;
    const size_t Epad = (size_t)nbC * CH * DEG;   // padded tile space

    // ws (~64.1 MB):
    char* w = (char*)d_ws;
    unsigned short* t1v1  = (unsigned short*)w;  w += Epad * H * 2;        // t1(fp16)/vals1(bf16) tiles
    unsigned short* Xn1b  = (unsigned short*)w;  w += (size_t)N * H * 2;
    unsigned short* Xn2b  = (unsigned short*)w;  w += (size_t)N * H * 2;
    float*          AsumP = (float*)w;           w += (size_t)N * H * 4;
    unsigned short* Wcat1 = (unsigned short*)w;  w += 32 * 192 * 2;
    unsigned short* Wcat2 = (unsigned short*)w;  w += 32 * 96 * 2;
    unsigned short* Wn1pb = (unsigned short*)w;  w += 32 * 128 * 2;
    float*          bias1 = (float*)w;           w += H * 4;
    float*          bias2 = (float*)w;           w += H * 4;
    float*          biasn1= (float*)w;           w += H * 4;
    float* outp = (float*)d_out;

    const int nb8 = (N + 7) / 8;

    k_prep<<<1, 256, 0, stream>>>(we1s, we1p, be1p, be1s, we2p, we2s, be2p, be2s,
                                  wn1p, bn1p, bn1s,
                                  Wcat1, Wcat2, Wn1pb, bias1, bias2, biasn1);
    k_p1<<<nbC, 256, 0, stream>>>(X, dst, D, Wcat1, Wn1pb, biasn1, t1v1, Xn1b, N);
    k_p2<<<nbC, 256, 0, stream>>>(dst, Xn1b, Wcat1, bias1, t1v1, AsumP, N);
    k_xn2<<<nb8, 256, 0, stream>>>(Xn1b, AsumP, D, wn2p, bn2p, wn2s, bn2s, Xn2b, N);
    k_p3<<<nbC, 256, 0, stream>>>(Xn2b, dst, t1v1, Wcat2, bias2, wc, bc, outp, N);
}

// Round 7
// 227.467 us; speedup vs baseline: 3.3102x; 1.2571x over previous
//
#include <hip/hip_runtime.h>

#define DEG 16
#define F_IN 128
#define H 32
#define CH 16   // nodes per chunk (= per block)

typedef __attribute__((ext_vector_type(8))) _Float16 f16x8;  // MFMA A/B frag (4 VGPRs)
typedef __attribute__((ext_vector_type(4))) float f32x4;     // MFMA C/D frag
typedef __attribute__((ext_vector_type(4))) int i32x4;

union HF4 { _Float16 h[4]; uint2 u; };                       // fp16 quad <-> 8B
union HS  { _Float16 f; unsigned short s; };

__device__ __forceinline__ float relu_f(float x) { return fmaxf(x, 0.0f); }

// packed |a| on 8 fp16 lanes: AND with 0x7FFF per half
__device__ __forceinline__ f16x8 habs8(f16x8 a) {
    union { f16x8 h; i32x4 i; } u; u.h = a;
#pragma unroll
    for (int k = 0; k < 4; ++k) u.i[k] &= 0x7FFF7FFF;
    return u.h;
}
__device__ __forceinline__ unsigned short f2h_s(float x) {
    HS v; v.f = (_Float16)x; return v.s;
}
__device__ __forceinline__ float h2f_s(unsigned short s) {
    HS v; v.s = s; return (float)v.f;
}

// ---------------------------------------------------------------------------
// X fp32 -> fp16 (one thread per 8 elements; grid exact for N*128 % 2048 == 0)
// ---------------------------------------------------------------------------
__global__ __launch_bounds__(256) void k_xhalf(
    const float* __restrict__ X, _Float16* __restrict__ Xh, long n8)
{
    const long t = (long)blockIdx.x * 256 + threadIdx.x;
    if (t >= n8) return;
    const float4* p = (const float4*)X + t * 2;
    const float4 a = p[0], b = p[1];
    f16x8 h;
    h[0] = (_Float16)a.x; h[1] = (_Float16)a.y; h[2] = (_Float16)a.z; h[3] = (_Float16)a.w;
    h[4] = (_Float16)b.x; h[5] = (_Float16)b.y; h[6] = (_Float16)b.z; h[7] = (_Float16)b.w;
    *(f16x8*)(Xh + t * 8) = h;
}

// ---------------------------------------------------------------------------
// Prep: fp16 weight blocks + pre-summed fp32 biases.
//  Wcat1[32][192]: k<128 -> we1s; 128..159 -> 0.5*we1p(diff); 160..191 -> 0.5*we1p(sum)
//  Wn1p [32][128]; Wcat2[32][96]: 0.5*we2p(diff)|0.5*we2p(sum)|we2s
//  Wn2p/Wn2s [32][32]
// ---------------------------------------------------------------------------
__global__ __launch_bounds__(256) void k_prep(
    const float* __restrict__ we1s, const float* __restrict__ we1p,
    const float* __restrict__ be1p, const float* __restrict__ be1s,
    const float* __restrict__ we2p, const float* __restrict__ we2s,
    const float* __restrict__ be2p, const float* __restrict__ be2s,
    const float* __restrict__ wn1p, const float* __restrict__ bn1p,
    const float* __restrict__ bn1s,
    const float* __restrict__ wn2p, const float* __restrict__ bn2p,
    const float* __restrict__ wn2s, const float* __restrict__ bn2s,
    _Float16* __restrict__ Wcat1, _Float16* __restrict__ Wcat2,
    _Float16* __restrict__ Wn1ph,
    _Float16* __restrict__ Wn2ph, _Float16* __restrict__ Wn2sh,
    float* __restrict__ bias1, float* __restrict__ bias2,
    float* __restrict__ biasn1, float* __restrict__ biasn2)
{
    const int tid = threadIdx.x;
    for (int idx = tid; idx < 32 * 192; idx += 256) {
        const int n = idx / 192, k = idx - n * 192;
        float w;
        if (k < 128)       w = we1s[n * 128 + k];
        else if (k < 160)  w = 0.5f * we1p[n * 64 + (k - 128)];
        else               w = 0.5f * we1p[n * 64 + 32 + (k - 160)];
        Wcat1[idx] = (_Float16)w;
    }
    for (int idx = tid; idx < 32 * 96; idx += 256) {
        const int n = idx / 96, k = idx - n * 96;
        float w;
        if (k < 32)       w = 0.5f * we2p[n * 64 + k];
        else if (k < 64)  w = 0.5f * we2p[n * 64 + 32 + (k - 32)];
        else              w = we2s[n * 32 + (k - 64)];
        Wcat2[idx] = (_Float16)w;
    }
    for (int idx = tid; idx < 32 * 128; idx += 256)
        Wn1ph[idx] = (_Float16)wn1p[idx];
    for (int idx = tid; idx < 32 * 32; idx += 256) {
        Wn2ph[idx] = (_Float16)wn2p[idx];
        Wn2sh[idx] = (_Float16)wn2s[idx];
    }
    if (tid < H) {
        bias1[tid]  = be1p[tid] + be1s[tid];
        bias2[tid]  = be2p[tid] + be2s[tid];
        biasn1[tid] = bn1p[tid] + bn1s[tid];
        biasn2[tid] = bn2p[tid] + bn2s[tid];
    }
}

// ---------------------------------------------------------------------------
// P1: block = 16-node chunk; wave = 4 tiles (16 nodes x one offset j).
//   All 16 dst-row loads hoisted before compute (one latency round).
//   t1 tile = |Xh[src]-Xh[dst]| @ we1s^T  -> fp16 C-layout
//   U accum = |ΔX| @ wn1p^T  (AGPRs over the wave's 4 j's) -> cross-wave LDS
//   reduce -> Xn1 = relu(U/D + biasn1) -> fp16
// ---------------------------------------------------------------------------
__global__ __launch_bounds__(256) void k_p1(
    const _Float16* __restrict__ Xh, const int* __restrict__ dst,
    const float* __restrict__ D,
    const _Float16* __restrict__ Wcat1, const _Float16* __restrict__ Wn1ph,
    const float* __restrict__ biasn1,
    _Float16* __restrict__ t1h, _Float16* __restrict__ Xn1h, int N)
{
    __shared__ int dsL[16 * 17];
    __shared__ float UacS[4][16 * 33];
    const int tid = threadIdx.x;
    const int wave = tid >> 6, lane = tid & 63;
    const int i0 = blockIdx.x * CH;
    {
        const int mm = tid >> 4, j = tid & 15;
        const int nd = (i0 + mm < N) ? (i0 + mm) : (N - 1);
        dsL[mm * 17 + j] = dst[nd * DEG + j];
    }
    __syncthreads();
    const int m = lane & 15, g = lane >> 4;
    const int srow = (i0 + m < N) ? (i0 + m) : (N - 1);

    // --- all loads up front ---
    f16x8 sv[4];
#pragma unroll
    for (int kb = 0; kb < 4; ++kb)
        sv[kb] = *(const f16x8*)(Xh + (size_t)srow * F_IN + kb * 32 + g * 8);
    int dj[4];
#pragma unroll
    for (int jj = 0; jj < 4; ++jj) dj[jj] = dsL[m * 17 + wave * 4 + jj];
    f16x8 tv[4][4];
#pragma unroll
    for (int jj = 0; jj < 4; ++jj)
#pragma unroll
        for (int kb = 0; kb < 4; ++kb)
            tv[jj][kb] = *(const f16x8*)(Xh + (size_t)dj[jj] * F_IN + kb * 32 + g * 8);
    f16x8 Bs[4][2], Bn[4][2];
#pragma unroll
    for (int kb = 0; kb < 4; ++kb)
#pragma unroll
        for (int t = 0; t < 2; ++t) {
            Bs[kb][t] = *(const f16x8*)(Wcat1 + (t * 16 + m) * 192 + kb * 32 + g * 8);
            Bn[kb][t] = *(const f16x8*)(Wn1ph + (t * 16 + m) * 128 + kb * 32 + g * 8);
        }

    f32x4 cn0 = {0.f,0.f,0.f,0.f}, cn1 = {0.f,0.f,0.f,0.f};
#pragma unroll
    for (int jj = 0; jj < 4; ++jj) {
        f32x4 cs0 = {0.f,0.f,0.f,0.f}, cs1 = {0.f,0.f,0.f,0.f};
#pragma unroll
        for (int kb = 0; kb < 4; ++kb) {
            const f16x8 a = habs8(sv[kb] - tv[jj][kb]);   // packed fp16 sub + abs
            cs0 = __builtin_amdgcn_mfma_f32_16x16x32_f16(a, Bs[kb][0], cs0, 0, 0, 0);
            cs1 = __builtin_amdgcn_mfma_f32_16x16x32_f16(a, Bs[kb][1], cs1, 0, 0, 0);
            cn0 = __builtin_amdgcn_mfma_f32_16x16x32_f16(a, Bn[kb][0], cn0, 0, 0, 0);
            cn1 = __builtin_amdgcn_mfma_f32_16x16x32_f16(a, Bn[kb][1], cn1, 0, 0, 0);
        }
        const size_t tb = ((size_t)blockIdx.x * 16 + wave * 4 + jj) * 512;
        HF4 a;
#pragma unroll
        for (int r = 0; r < 4; ++r) a.h[r] = (_Float16)cs0[r];
        *(uint2*)(t1h + tb + lane * 4) = a.u;
#pragma unroll
        for (int r = 0; r < 4; ++r) a.h[r] = (_Float16)cs1[r];
        *(uint2*)(t1h + tb + 256 + lane * 4) = a.u;
    }
    // cross-wave reduce of U -> Xn1   (C layout: col=m=feature, row=g*4+r=node)
#pragma unroll
    for (int r = 0; r < 4; ++r) {
        UacS[wave][(g * 4 + r) * 33 + m]      = cn0[r];
        UacS[wave][(g * 4 + r) * 33 + 16 + m] = cn1[r];
    }
    __syncthreads();
    {
        const int mm = tid >> 4, c = tid & 15;
        float u0 = 0.f, u1 = 0.f;
#pragma unroll
        for (int w = 0; w < 4; ++w) {
            u0 += UacS[w][mm * 33 + c];
            u1 += UacS[w][mm * 33 + 16 + c];
        }
        if (i0 + mm < N) {
            const float invD = 1.0f / D[i0 + mm];
            Xn1h[(size_t)(i0 + mm) * H + c]      = (_Float16)relu_f(u0 * invD + biasn1[c]);
            Xn1h[(size_t)(i0 + mm) * H + 16 + c] = (_Float16)relu_f(u1 * invD + biasn1[16 + c]);
        }
    }
}

// ---------------------------------------------------------------------------
// P2: finish edge_conv1 per tile (C init = t1 fp16; + Ef1 @ folded we1p).
//   vals1 tile -> fp16 TILE-MAJOR, in place over t1 buffer.
//   Asum stays in LDS; wave 0 computes Xn2 = relu(Asum/D@wn2p + Xn1@wn2s + b)
//   with 4 MFMAs (k_xn2 folded in). All jj loads hoisted.
// ---------------------------------------------------------------------------
__global__ __launch_bounds__(256) void k_p2(
    const int* __restrict__ dst, const _Float16* __restrict__ Xn1h,
    const _Float16* __restrict__ Wcat1, const float* __restrict__ bias1,
    const _Float16* __restrict__ Wn2ph, const _Float16* __restrict__ Wn2sh,
    const float* __restrict__ biasn2, const float* __restrict__ D,
    _Float16* t1v1,                 // read t1, write vals1 (same buffer)
    _Float16* __restrict__ Xn2h, int N)
{
    __shared__ int dsL[16 * 17];
    __shared__ unsigned short RP[4][16 * 40];
    __shared__ float AacS[4][16 * 33];
    __shared__ unsigned short AsumH[16 * 40];   // fp16 Asum/D, A-frag readable
    const int tid = threadIdx.x;
    const int wave = tid >> 6, lane = tid & 63;
    const int i0 = blockIdx.x * CH;
    {
        const int mm = tid >> 4, j = tid & 15;
        const int nd = (i0 + mm < N) ? (i0 + mm) : (N - 1);
        dsL[mm * 17 + j] = dst[nd * DEG + j];
    }
    __syncthreads();
    const int m = lane & 15, g = lane >> 4;
    const int srow = (i0 + m < N) ? (i0 + m) : (N - 1);

    // --- all loads up front ---
    const f16x8 x1 = *(const f16x8*)(Xn1h + (size_t)srow * H + g * 8);
    int dj[4];
#pragma unroll
    for (int jj = 0; jj < 4; ++jj) dj[jj] = dsL[m * 17 + wave * 4 + jj];
    f16x8 x2[4];
#pragma unroll
    for (int jj = 0; jj < 4; ++jj)
        x2[jj] = *(const f16x8*)(Xn1h + (size_t)dj[jj] * H + g * 8);
    uint2 ta[4], tbv[4];
#pragma unroll
    for (int jj = 0; jj < 4; ++jj) {
        const size_t tb = ((size_t)blockIdx.x * 16 + wave * 4 + jj) * 512;
        ta[jj]  = *(const uint2*)(t1v1 + tb + lane * 4);
        tbv[jj] = *(const uint2*)(t1v1 + tb + 256 + lane * 4);
    }
    f16x8 Bf[2][2];
#pragma unroll
    for (int kb = 0; kb < 2; ++kb)
#pragma unroll
        for (int t = 0; t < 2; ++t)
            Bf[kb][t] = *(const f16x8*)(Wcat1 + (t * 16 + m) * 192 + (4 + kb) * 32 + g * 8);

    const float b0 = bias1[m], b1v = bias1[16 + m];
    float sA0[4] = {0.f,0.f,0.f,0.f}, sA1[4] = {0.f,0.f,0.f,0.f};
    unsigned short* L = RP[wave];
#pragma unroll
    for (int jj = 0; jj < 4; ++jj) {
        f32x4 c0, c1;
        { HF4 a; a.u = ta[jj];
#pragma unroll
          for (int r = 0; r < 4; ++r) c0[r] = (float)a.h[r];
          a.u = tbv[jj];
#pragma unroll
          for (int r = 0; r < 4; ++r) c1[r] = (float)a.h[r]; }
        const f16x8 ad = x1 - x2[jj];
        const f16x8 aS = x1 + x2[jj];
        c0 = __builtin_amdgcn_mfma_f32_16x16x32_f16(ad, Bf[0][0], c0, 0, 0, 0);
        c1 = __builtin_amdgcn_mfma_f32_16x16x32_f16(ad, Bf[0][1], c1, 0, 0, 0);
        c0 = __builtin_amdgcn_mfma_f32_16x16x32_f16(aS, Bf[1][0], c0, 0, 0, 0);
        c1 = __builtin_amdgcn_mfma_f32_16x16x32_f16(aS, Bf[1][1], c1, 0, 0, 0);
#pragma unroll
        for (int r = 0; r < 4; ++r) {
            const float v0 = relu_f(c0[r] + b0);
            const float v1 = relu_f(c1[r] + b1v);
            L[(g * 4 + r) * 40 + m]      = f2h_s(v0);
            L[(g * 4 + r) * 40 + 16 + m] = f2h_s(v1);
            sA0[r] += v0; sA1[r] += v1;
        }
        // repack to tile-major fp16, dense 16B stores (in place over t1)
        const size_t tb = ((size_t)blockIdx.x * 16 + wave * 4 + jj) * 512;
        const int rr = lane >> 2, q = lane & 3;
        const i32x4 v = *(const i32x4*)(L + rr * 40 + q * 8);
        *(i32x4*)(t1v1 + tb + rr * 32 + q * 8) = v;
    }
#pragma unroll
    for (int r = 0; r < 4; ++r) {
        AacS[wave][(g * 4 + r) * 33 + m]      = sA0[r];
        AacS[wave][(g * 4 + r) * 33 + 16 + m] = sA1[r];
    }
    __syncthreads();
    {
        const int mm = tid >> 4, c = tid & 15;
        float a0 = 0.f, a1 = 0.f;
#pragma unroll
        for (int w = 0; w < 4; ++w) {
            a0 += AacS[w][mm * 33 + c];
            a1 += AacS[w][mm * 33 + 16 + c];
        }
        const int nd = (i0 + mm < N) ? (i0 + mm) : (N - 1);
        const float invD = 1.0f / D[nd];
        AsumH[mm * 40 + c]      = f2h_s(a0 * invD);
        AsumH[mm * 40 + 16 + c] = f2h_s(a1 * invD);
    }
    __syncthreads();
    if (wave == 0) {   // node_conv2 for the block's 16 nodes: 4 MFMAs
        const f16x8 aF = *(const f16x8*)((const _Float16*)AsumH + m * 40 + g * 8);
        f16x8 Bp[2], Bs2[2];
#pragma unroll
        for (int t = 0; t < 2; ++t) {
            Bp[t]  = *(const f16x8*)(Wn2ph + (t * 16 + m) * H + g * 8);
            Bs2[t] = *(const f16x8*)(Wn2sh + (t * 16 + m) * H + g * 8);
        }
        f32x4 c0 = {0.f,0.f,0.f,0.f}, c1 = {0.f,0.f,0.f,0.f};
        c0 = __builtin_amdgcn_mfma_f32_16x16x32_f16(aF, Bp[0], c0, 0, 0, 0);
        c1 = __builtin_amdgcn_mfma_f32_16x16x32_f16(aF, Bp[1], c1, 0, 0, 0);
        c0 = __builtin_amdgcn_mfma_f32_16x16x32_f16(x1, Bs2[0], c0, 0, 0, 0);
        c1 = __builtin_amdgcn_mfma_f32_16x16x32_f16(x1, Bs2[1], c1, 0, 0, 0);
        const float bp0 = biasn2[m], bp1 = biasn2[16 + m];
#pragma unroll
        for (int r = 0; r < 4; ++r) {
            const int node = i0 + g * 4 + r;
            if (node < N) {
                Xn2h[(size_t)node * H + m]      = (_Float16)relu_f(c0[r] + bp0);
                Xn2h[(size_t)node * H + 16 + m] = (_Float16)relu_f(c1[r] + bp1);
            }
        }
    }
}

// ---------------------------------------------------------------------------
// P3: layer-2 edge conv + classifier + sigmoid. All jj loads hoisted, fp16.
// ---------------------------------------------------------------------------
__global__ __launch_bounds__(256) void k_p3(
    const _Float16* __restrict__ Xn2h, const int* __restrict__ dst,
    const _Float16* __restrict__ vals1,
    const _Float16* __restrict__ Wcat2, const float* __restrict__ bias2,
    const float* __restrict__ wc, const float* __restrict__ bc,
    float* __restrict__ out, int N)
{
    __shared__ int dsL[16 * 17];
    __shared__ float outS[16 * 17];
    const int tid = threadIdx.x;
    const int wave = tid >> 6, lane = tid & 63;
    const int i0 = blockIdx.x * CH;
    {
        const int mm = tid >> 4, j = tid & 15;
        const int nd = (i0 + mm < N) ? (i0 + mm) : (N - 1);
        dsL[mm * 17 + j] = dst[nd * DEG + j];
    }
    __syncthreads();
    const int m = lane & 15, g = lane >> 4;
    const int srow = (i0 + m < N) ? (i0 + m) : (N - 1);

    // --- all loads up front ---
    const f16x8 x1 = *(const f16x8*)(Xn2h + (size_t)srow * H + g * 8);
    int dj[4];
#pragma unroll
    for (int jj = 0; jj < 4; ++jj) dj[jj] = dsL[m * 17 + wave * 4 + jj];
    f16x8 x2[4], av[4];
#pragma unroll
    for (int jj = 0; jj < 4; ++jj) {
        x2[jj] = *(const f16x8*)(Xn2h + (size_t)dj[jj] * H + g * 8);
        const size_t tb = ((size_t)blockIdx.x * 16 + wave * 4 + jj) * 512;
        av[jj] = *(const f16x8*)(vals1 + tb + m * 32 + g * 8);
    }
    f16x8 Bf[3][2];
#pragma unroll
    for (int kb = 0; kb < 3; ++kb)
#pragma unroll
        for (int t = 0; t < 2; ++t)
            Bf[kb][t] = *(const f16x8*)(Wcat2 + (t * 16 + m) * 96 + kb * 32 + g * 8);

    const float b0 = bias2[m], b1v = bias2[16 + m];
    const float w0 = wc[m], w1 = wc[16 + m];
#pragma unroll
    for (int jj = 0; jj < 4; ++jj) {
        const f16x8 ad = x1 - x2[jj];
        const f16x8 aS = x1 + x2[jj];
        f32x4 c0 = {0.f,0.f,0.f,0.f}, c1 = {0.f,0.f,0.f,0.f};
        c0 = __builtin_amdgcn_mfma_f32_16x16x32_f16(ad,     Bf[0][0], c0, 0, 0, 0);
        c1 = __builtin_amdgcn_mfma_f32_16x16x32_f16(ad,     Bf[0][1], c1, 0, 0, 0);
        c0 = __builtin_amdgcn_mfma_f32_16x16x32_f16(aS,     Bf[1][0], c0, 0, 0, 0);
        c1 = __builtin_amdgcn_mfma_f32_16x16x32_f16(aS,     Bf[1][1], c1, 0, 0, 0);
        c0 = __builtin_amdgcn_mfma_f32_16x16x32_f16(av[jj], Bf[2][0], c0, 0, 0, 0);
        c1 = __builtin_amdgcn_mfma_f32_16x16x32_f16(av[jj], Bf[2][1], c1, 0, 0, 0);

        float sr[4];
#pragma unroll
        for (int r = 0; r < 4; ++r)
            sr[r] = relu_f(c0[r] + b0) * w0 + relu_f(c1[r] + b1v) * w1;
#pragma unroll
        for (int mask = 1; mask < 16; mask <<= 1) {
#pragma unroll
            for (int r = 0; r < 4; ++r)
                sr[r] += __shfl_xor(sr[r], mask);
        }
        if (m == 0) {
#pragma unroll
            for (int r = 0; r < 4; ++r)
                outS[(g * 4 + r) * 17 + (wave * 4 + jj)] = sr[r];
        }
    }
    __syncthreads();
    {
        const int mm = tid >> 4;
        if (i0 + mm < N) {
            const float sx = outS[mm * 17 + (tid & 15)] + bc[0];
            out[(size_t)i0 * DEG + tid] = 1.0f / (1.0f + __expf(-sx));
        }
    }
}

// ---------------------------------------------------------------------------
extern "C" void kernel_launch(void* const* d_in, const int* in_sizes, int n_in,
                              void* d_out, int out_size, void* d_ws, size_t ws_size,
                              hipStream_t stream)
{
    const float* X    = (const float*)d_in[0];
    const int*   dst  = (const int*)  d_in[2];
    const float* D    = (const float*)d_in[3];
    const float* wn1p = (const float*)d_in[4];
    const float* bn1p = (const float*)d_in[5];
    // d_in[6] = wn1s unused: X0 == zeros, self term reduces to bn1s.
    const float* bn1s = (const float*)d_in[7];
    const float* we1p = (const float*)d_in[8];
    const float* be1p = (const float*)d_in[9];
    const float* we1s = (const float*)d_in[10];
    const float* be1s = (const float*)d_in[11];
    const float* wn2p = (const float*)d_in[12];
    const float* bn2p = (const float*)d_in[13];
    const float* wn2s = (const float*)d_in[14];
    const float* bn2s = (const float*)d_in[15];
    const float* we2p = (const float*)d_in[16];
    const float* be2p = (const float*)d_in[17];
    const float* we2s = (const float*)d_in[18];
    const float* be2s = (const float*)d_in[19];
    const float* wc   = (const float*)d_in[20];
    const float* bc   = (const float*)d_in[21];

    const int N = in_sizes[3];        // D has one entry per node
    const int nbC = (N + CH - 1) / CH;
    const size_t Epad = (size_t)nbC * CH * DEG;

    // ws (~70.6 MB):
    char* w = (char*)d_ws;
    _Float16* t1v1  = (_Float16*)w;  w += Epad * H * 2;          // t1/vals1 tiles (fp16)
    _Float16* Xh    = (_Float16*)w;  w += (size_t)N * F_IN * 2;  // X fp16
    _Float16* Xn1h  = (_Float16*)w;  w += (size_t)N * H * 2;
    _Float16* Xn2h  = (_Float16*)w;  w += (size_t)N * H * 2;
    _Float16* Wcat1 = (_Float16*)w;  w += 32 * 192 * 2;
    _Float16* Wcat2 = (_Float16*)w;  w += 32 * 96 * 2;
    _Float16* Wn1ph = (_Float16*)w;  w += 32 * 128 * 2;
    _Float16* Wn2ph = (_Float16*)w;  w += 32 * 32 * 2;
    _Float16* Wn2sh = (_Float16*)w;  w += 32 * 32 * 2;
    float* bias1  = (float*)w;       w += H * 4;
    float* bias2  = (float*)w;       w += H * 4;
    float* biasn1 = (float*)w;       w += H * 4;
    float* biasn2 = (float*)w;       w += H * 4;
    float* outp = (float*)d_out;

    const long n8 = (long)N * F_IN / 8;
    const int nbX = (int)((n8 + 255) / 256);

    k_xhalf<<<nbX, 256, 0, stream>>>(X, Xh, n8);
    k_prep<<<1, 256, 0, stream>>>(we1s, we1p, be1p, be1s, we2p, we2s, be2p, be2s,
                                  wn1p, bn1p, bn1s, wn2p, bn2p, wn2s, bn2s,
                                  Wcat1, Wcat2, Wn1ph, Wn2ph, Wn2sh,
                                  bias1, bias2, biasn1, biasn2);
    k_p1<<<nbC, 256, 0, stream>>>(Xh, dst, D, Wcat1, Wn1ph, biasn1, t1v1, Xn1h, N);
    k_p2<<<nbC, 256, 0, stream>>>(dst, Xn1h, Wcat1, bias1, Wn2ph, Wn2sh, biasn2, D,
                                  t1v1, Xn2h, N);
    k_p3<<<nbC, 256, 0, stream>>>(Xn2h, dst, t1v1, Wcat2, bias2, wc, bc, outp, N);
}